// Round 7
// baseline (176.325 us; speedup 1.0000x reference)
//
#include <hip/hip_runtime.h>
#include <hip/hip_bf16.h>

#define B_ 4
#define I_ 512
#define J_ 512
#define C_ 512
#define P_ 128
#define H_ 4
#define D_ 32
#define HD_ 128
#define EPS_ 1e-5f
#define INF_ 1.0e9f
#define QSCALE_ 0.17677669529663689f

typedef __attribute__((ext_vector_type(8))) short bf16x8;
typedef __attribute__((ext_vector_type(4))) short s16x4;
typedef __attribute__((ext_vector_type(4))) float f32x4;

// fp32 -> bf16 raw bits; plain cast lets the compiler pack v_cvt_pk_bf16_f32
__device__ __forceinline__ short f2bf(float f) {
    return __bfloat16_as_short(__float2bfloat16(f));
}

// ---------------------------------------------------------------------------
// K1: merged prep.
//   blocks 0..1023:    LayerNorm of node_i / node_j (4 rows/block, wave/row)
//   block 1024:        fold LN gamma into pair->head weights (MFMA B-frags)
//                      + AB[16] via LDS-parallel reduce
//   blocks 1025..1152: transpose {wq,wk,wv,wg} -> wT[m][col][c] bf16
//                      (q-scale folded into wT[0]); 32 blocks per matrix
// grid: 1153 blocks, 256 threads
// ---------------------------------------------------------------------------
__global__ __launch_bounds__(256) void k_prep(
    const float* __restrict__ xi, const float* __restrict__ xj,
    const float* __restrict__ g_i, const float* __restrict__ b_i,
    const float* __restrict__ g_j, const float* __restrict__ b_j,
    const float* __restrict__ lng, const float* __restrict__ lnb,
    const float* __restrict__ wpb, const float* __restrict__ wpg,
    const float* __restrict__ wq, const float* __restrict__ wk,
    const float* __restrict__ wv, const float* __restrict__ wg,
    float* __restrict__ ni, float* __restrict__ nj,
    short* __restrict__ gwfB, float* __restrict__ AB,
    short* __restrict__ wT)
{
    const int bx  = blockIdx.x;
    const int tid = threadIdx.x;

    if (bx < 1024) {
        const int which = bx >> 9;
        const float* x  = which ? xj  : xi;
        const float* gg = which ? g_j : g_i;
        const float* bb = which ? b_j : b_i;
        float* o        = which ? nj  : ni;

        const int row  = (bx & 511) * 4 + (tid >> 6);
        const int lane = tid & 63;

        const float* xr = x + (size_t)row * C_ + lane * 8;
        float4 v0 = *(const float4*)xr;
        float4 v1 = *(const float4*)(xr + 4);

        float s  = v0.x + v0.y + v0.z + v0.w + v1.x + v1.y + v1.z + v1.w;
        float sq = v0.x*v0.x + v0.y*v0.y + v0.z*v0.z + v0.w*v0.w
                 + v1.x*v1.x + v1.y*v1.y + v1.z*v1.z + v1.w*v1.w;
#pragma unroll
        for (int m = 1; m <= 32; m <<= 1) {
            s  += __shfl_xor(s, m);
            sq += __shfl_xor(sq, m);
        }
        const float mean = s * (1.0f / C_);
        const float var  = sq * (1.0f / C_) - mean * mean;
        const float rstd = rsqrtf(var + EPS_);

        float4 ga  = *(const float4*)(gg + lane * 8);
        float4 gb  = *(const float4*)(gg + lane * 8 + 4);
        float4 ba  = *(const float4*)(bb + lane * 8);
        float4 bb4 = *(const float4*)(bb + lane * 8 + 4);

        float4 r0, r1;
        r0.x = (v0.x - mean) * rstd * ga.x + ba.x;
        r0.y = (v0.y - mean) * rstd * ga.y + ba.y;
        r0.z = (v0.z - mean) * rstd * ga.z + ba.z;
        r0.w = (v0.w - mean) * rstd * ga.w + ba.w;
        r1.x = (v1.x - mean) * rstd * gb.x + bb4.x;
        r1.y = (v1.y - mean) * rstd * gb.y + bb4.y;
        r1.z = (v1.z - mean) * rstd * gb.z + bb4.z;
        r1.w = (v1.w - mean) * rstd * gb.w + bb4.w;

        float* orow = o + (size_t)row * C_ + lane * 8;
        *(float4*)orow       = r0;
        *(float4*)(orow + 4) = r1;
    } else if (bx == 1024) {
        // ---- fold path ----
        __shared__ float sAB[P_ * 16];
        const int s = tid >> 6, lane = tid & 63;
        const int c = lane >> 4, n = lane & 15;
#pragma unroll
        for (int e = 0; e < 8; e++) {
            const int p = s * 32 + c * 8 + e;
            const float w = (n < 4) ? wpb[p * 4 + n]
                          : (n < 8) ? wpg[p * 4 + (n - 4)] : 0.0f;
            gwfB[(s * 64 + lane) * 8 + e] = f2bf(lng[p] * w);
        }
        if (tid < P_) {
            const int p = tid;
            const float g = lng[p], b = lnb[p];
#pragma unroll
            for (int h = 0; h < 4; h++) {
                const float wb = wpb[p * 4 + h], wgv = wpg[p * 4 + h];
                sAB[p * 16 + h]      = g * wb;
                sAB[p * 16 + 4 + h]  = g * wgv;
                sAB[p * 16 + 8 + h]  = b * wb;
                sAB[p * 16 + 12 + h] = b * wgv;
            }
        }
        __syncthreads();
        if (tid < 16) {
            float a = 0.0f;
            for (int p = 0; p < P_; p++) a += sAB[p * 16 + tid];
            AB[tid] = a;
        }
    } else {
        // ---- weight transpose: 128 blocks, 4 cols each, 8 c per thread ----
        const int bx2 = bx - 1025;          // 0..127
        const int m   = bx2 >> 5, sub = bx2 & 31;
        const float* W = (m == 0) ? wq : (m == 1) ? wk : (m == 2) ? wv : wg;
        const float scale = (m == 0) ? QSCALE_ : 1.0f;
        const int col = sub * 4 + (tid >> 6);
        const int c0  = (tid & 63) * 8;
        bf16x8 pk;
#pragma unroll
        for (int u = 0; u < 8; u++)
            pk[u] = f2bf(W[(size_t)(c0 + u) * HD_ + col] * scale);
        *(bf16x8*)(wT + m * 65536 + col * 512 + c0) = pk;
    }
}

// ---------------------------------------------------------------------------
// pair-tile helpers (registers only; fully inlined)
// ---------------------------------------------------------------------------
__device__ __forceinline__ void pb_load(
    f32x4 (&xa)[4], f32x4 (&xb)[4], float& pm, int tile,
    const float* __restrict__ pair, const int* __restrict__ pmask,
    int r, int c)
{
    const float* xp = pair + ((size_t)tile * 16 + r) * P_ + c * 8;
#pragma unroll
    for (int s = 0; s < 4; s++) {
        xa[s] = *(const f32x4*)(xp + s * 32);
        xb[s] = *(const f32x4*)(xp + s * 32 + 4);
    }
    pm = (float)pmask[tile * 16 + r];
}

// compute one 16-j pair tile; ADD (bias+mask) into LDS logits
// logits layout: float at s_mem + h*16384 + i_l*2048, index j
__device__ __forceinline__ void pb_compute_lds(
    const f32x4 (&xa)[4], const f32x4 (&xb)[4], float pm,
    const bf16x8 (&bfrag)[4], float Al, float Ag, float Bl, float Bg,
    char* __restrict__ s_mem, int i_l, int jt, int lane, int r, int c)
{
    f32x4 acc = {0.0f, 0.0f, 0.0f, 0.0f};
    float sum = 0.0f, sq = 0.0f;
#pragma unroll
    for (int s = 0; s < 4; s++) {
        const float e0 = xa[s].x, e1 = xa[s].y, e2 = xa[s].z, e3 = xa[s].w;
        const float e4 = xb[s].x, e5 = xb[s].y, e6 = xb[s].z, e7 = xb[s].w;
        sum += e0 + e1 + e2 + e3 + e4 + e5 + e6 + e7;
        sq = fmaf(e0, e0, sq); sq = fmaf(e1, e1, sq);
        sq = fmaf(e2, e2, sq); sq = fmaf(e3, e3, sq);
        sq = fmaf(e4, e4, sq); sq = fmaf(e5, e5, sq);
        sq = fmaf(e6, e6, sq); sq = fmaf(e7, e7, sq);
        bf16x8 afrag;
        afrag[0] = f2bf(e0); afrag[1] = f2bf(e1);
        afrag[2] = f2bf(e2); afrag[3] = f2bf(e3);
        afrag[4] = f2bf(e4); afrag[5] = f2bf(e5);
        afrag[6] = f2bf(e6); afrag[7] = f2bf(e7);
        acc = __builtin_amdgcn_mfma_f32_16x16x32_bf16(afrag, bfrag[s], acc, 0, 0, 0);
    }

    sum += __shfl_xor(sum, 16); sum += __shfl_xor(sum, 32);
    sq  += __shfl_xor(sq, 16);  sq  += __shfl_xor(sq, 32);
    const float mean = sum * (1.0f / P_);
    const float rstd = rsqrtf(sq * (1.0f / P_) - mean * mean + EPS_);
    const float mr   = mean * rstd;
    const float mb   = INF_ * (pm - 1.0f);

    // head = r (valid for r<4); logits row base for this (head, i_l)
    float* Lrow = (float*)(s_mem + r * 16384 + i_l * 2048);
#pragma unroll
    for (int reg = 0; reg < 4; reg++) {
        const int rr = c * 4 + reg;                    // j within tile
        const float rstd_r = __shfl(rstd, rr);
        const float mr_r   = __shfl(mr, rr);
        const float mb_r   = __shfl(mb, rr);
        const float Sg     = __shfl(acc[reg], lane + 4);  // gate col = head+4, same c-group
        if (r < 4) {
            const float left = fmaf(rstd_r, acc[reg], fmaf(-mr_r, Al, Bl));
            const float glog = fmaf(rstd_r, Sg,       fmaf(-mr_r, Ag, Bg));
            const float val  = left * (1.0f / (1.0f + __expf(-glog))) + mb_r;
            Lrow[jt * 16 + rr] += val;
        }
    }
}

// ---------------------------------------------------------------------------
// K3: MEGA kernel: QK^T -> LDS logits; pair-bias stream ADDs into logits;
// softmax in-place (P bf16, XOR-swizzled, padded to 16 rows); PV -> o_ws.
// Block = (b, 4-i quad), 8 waves (512 thr), 64KB LDS -> 2 blocks/CU.
// grid: 512 blocks
// ---------------------------------------------------------------------------
__global__ __launch_bounds__(512, 4) void k_mega(
    const float* __restrict__ pair, const int* __restrict__ pmask,
    const short* __restrict__ gwfB, const float* __restrict__ AB,
    const short* __restrict__ q_bf, const short* __restrict__ k_bf,
    const short* __restrict__ vT_bf, float* __restrict__ o_ws)
{
    __shared__ float s_mem_f[16384];           // 64 KB union: logits f32 / P bf16
    __shared__ float s_sum[16];
    char* s_mem = (char*)s_mem_f;

    const int tid  = threadIdx.x;
    const int w    = tid >> 6;                 // 0..7
    const int lane = tid & 63;
    const int r    = lane & 15;
    const int c    = lane >> 4;
    const int b    = blockIdx.x >> 7;
    const int i0   = (blockIdx.x & 127) * 4;   // global i base

    // ---- pair constants ----
    bf16x8 bfrag[4];
#pragma unroll
    for (int s = 0; s < 4; s++)
        bfrag[s] = *(const bf16x8*)(gwfB + (s * 64 + lane) * 8);
    const int n4 = r & 3;
    const float Al = AB[n4], Ag = AB[4 + n4];
    const float Bl = AB[8 + n4], Bg = AB[12 + n4];

    // ---- prologue: issue first pair tile loads (hide under QK) ----
    f32x4 xa0[4], xb0[4], xa1[4], xb1[4];
    float pm0, pm1;
    {
        const int iA = w * 16;
        pb_load(xa0, xb0, pm0, (b * 512 + i0 + (iA >> 5)) * 32 + (iA & 31),
                pair, pmask, r, c);
    }

    // ---- QK phase: 16 (h,jt) units per wave; write logits ----
#pragma unroll
    for (int k6 = 0; k6 < 16; k6++) {
        const int u  = w * 16 + k6;
        const int h  = u >> 5, jt = u & 31;
        const bf16x8 qf = *(const bf16x8*)(q_bf + ((size_t)(b * 4 + h) * 512 + i0 + r) * 32 + c * 8);
        const bf16x8 kf = *(const bf16x8*)(k_bf + ((size_t)(b * 4 + h) * 512 + jt * 16 + r) * 32 + c * 8);
        f32x4 z = {0.0f, 0.0f, 0.0f, 0.0f};
        z = __builtin_amdgcn_mfma_f32_16x16x32_bf16(qf, kf, z, 0, 0, 0);
        if (c == 0) {
            float* Lp = (float*)(s_mem + h * 16384);
#pragma unroll
            for (int reg = 0; reg < 4; reg++)
                Lp[reg * 512 + jt * 16 + r] = z[reg];   // i_l = reg
        }
    }
    __syncthreads();   // logits initialized

    // ---- pair stream: 16 tiles/wave, 2-deep prefetch, add into logits ----
#pragma unroll
    for (int it = 0; it < 16; it += 2) {
        const int iA = w * 16 + it, iB = iA + 1;
        pb_load(xa1, xb1, pm1, (b * 512 + i0 + (iB >> 5)) * 32 + (iB & 31),
                pair, pmask, r, c);
        pb_compute_lds(xa0, xb0, pm0, bfrag, Al, Ag, Bl, Bg,
                       s_mem, iA >> 5, iA & 31, lane, r, c);
        if (it + 2 < 16) {
            const int iC = iA + 2;
            pb_load(xa0, xb0, pm0, (b * 512 + i0 + (iC >> 5)) * 32 + (iC & 31),
                    pair, pmask, r, c);
        }
        pb_compute_lds(xa1, xb1, pm1, bfrag, Al, Ag, Bl, Bg,
                       s_mem, iB >> 5, iB & 31, lane, r, c);
    }
    __syncthreads();   // all logits complete

    // ---- softmax: wave owns rows w*2, w*2+1 (row = h*4 + i) ----
    float pv0[8], pv1[8];
    float S0 = 0.0f, S1 = 0.0f;
    {
        const int row = w * 2;
        const int h = row >> 2, i = row & 3;
        const float* Lrow = (const float*)(s_mem + h * 16384 + i * 2048);
        const f32x4 a = *(const f32x4*)(Lrow + lane * 8);
        const f32x4 d = *(const f32x4*)(Lrow + lane * 8 + 4);
        float M = fmaxf(fmaxf(fmaxf(a.x, a.y), fmaxf(a.z, a.w)),
                        fmaxf(fmaxf(d.x, d.y), fmaxf(d.z, d.w)));
#pragma unroll
        for (int m = 1; m <= 32; m <<= 1) M = fmaxf(M, __shfl_xor(M, m));
        pv0[0] = __expf(a.x - M); pv0[1] = __expf(a.y - M);
        pv0[2] = __expf(a.z - M); pv0[3] = __expf(a.w - M);
        pv0[4] = __expf(d.x - M); pv0[5] = __expf(d.y - M);
        pv0[6] = __expf(d.z - M); pv0[7] = __expf(d.w - M);
#pragma unroll
        for (int e = 0; e < 8; e++) S0 += pv0[e];
#pragma unroll
        for (int m = 1; m <= 32; m <<= 1) S0 += __shfl_xor(S0, m);
    }
    {
        const int row = w * 2 + 1;
        const int h = row >> 2, i = row & 3;
        const float* Lrow = (const float*)(s_mem + h * 16384 + i * 2048);
        const f32x4 a = *(const f32x4*)(Lrow + lane * 8);
        const f32x4 d = *(const f32x4*)(Lrow + lane * 8 + 4);
        float M = fmaxf(fmaxf(fmaxf(a.x, a.y), fmaxf(a.z, a.w)),
                        fmaxf(fmaxf(d.x, d.y), fmaxf(d.z, d.w)));
#pragma unroll
        for (int m = 1; m <= 32; m <<= 1) M = fmaxf(M, __shfl_xor(M, m));
        pv1[0] = __expf(a.x - M); pv1[1] = __expf(a.y - M);
        pv1[2] = __expf(a.z - M); pv1[3] = __expf(a.w - M);
        pv1[4] = __expf(d.x - M); pv1[5] = __expf(d.y - M);
        pv1[6] = __expf(d.z - M); pv1[7] = __expf(d.w - M);
#pragma unroll
        for (int e = 0; e < 8; e++) S1 += pv1[e];
#pragma unroll
        for (int m = 1; m <= 32; m <<= 1) S1 += __shfl_xor(S1, m);
    }
    __syncthreads();   // all logits reads complete

    // ---- write P bf16 (swizzled) + sums + zero pad rows ----
    {
        const int row = w * 2;
        const int h = row >> 2, i = row & 3;
        bf16x8 pk;
#pragma unroll
        for (int e = 0; e < 8; e++) pk[e] = f2bf(pv0[e]);
        *(bf16x8*)(s_mem + h * 16384 + i * 1024 + ((lane * 16) ^ ((i & 7) << 4))) = pk;
        if (lane == 0) s_sum[row] = S0;
    }
    {
        const int row = w * 2 + 1;
        const int h = row >> 2, i = row & 3;
        bf16x8 pk;
#pragma unroll
        for (int e = 0; e < 8; e++) pk[e] = f2bf(pv1[e]);
        *(bf16x8*)(s_mem + h * 16384 + i * 1024 + ((lane * 16) ^ ((i & 7) << 4))) = pk;
        if (lane == 0) s_sum[row] = S1;
    }
    {
        const f32x4 z4 = {0.0f, 0.0f, 0.0f, 0.0f};
#pragma unroll
        for (int h2 = 0; h2 < 4; h2++) {
            char* pb = s_mem + h2 * 16384 + 4096;     // P rows 4..15 = 12 KB
            *(f32x4*)(pb + tid * 16) = z4;            // 8 KB
            if (tid < 256) *(f32x4*)(pb + 8192 + tid * 16) = z4;  // 4 KB
        }
    }
    __syncthreads();

    // ---- PV: wave = (h = w>>1, dt = w&1) ----
    {
        const int h = w >> 1, dt = w & 1;
        f32x4 oacc = {0.0f, 0.0f, 0.0f, 0.0f};
        const short* vrow = vT_bf + ((size_t)(b * 4 + h) * 32 + dt * 16 + r) * 512 + c * 8;
        const char* Pb = s_mem + h * 16384;
#pragma unroll
        for (int kk = 0; kk < 16; kk++) {
            const bf16x8 pf = *(const bf16x8*)(Pb + ((r * 1024 + kk * 64 + c * 16) ^ ((r & 7) << 4)));
            const bf16x8 vf = *(const bf16x8*)(vrow + kk * 32);
            oacc = __builtin_amdgcn_mfma_f32_16x16x32_bf16(pf, vf, oacc, 0, 0, 0);
        }
        if (c == 0) {
#pragma unroll
            for (int reg = 0; reg < 4; reg++) {
                const float rs = 1.0f / s_sum[h * 4 + reg];
                o_ws[((size_t)(b * 512 + i0 + reg)) * HD_ + h * 32 + dt * 16 + r] = oacc[reg] * rs;
            }
        }
    }
}

// ---------------------------------------------------------------------------
// K2: projections via bf16 MFMA (verified R5 version).
// grid: (B*I/32, 4), block: 128 (2 waves)
// ---------------------------------------------------------------------------
__global__ __launch_bounds__(128) void k_proj(
    const float* __restrict__ ni, const float* __restrict__ nj,
    const short* __restrict__ wT, const float* __restrict__ bg,
    short* __restrict__ q_bf, short* __restrict__ k_bf,
    short* __restrict__ vT_bf, float* __restrict__ g_ws)
{
    const int m    = blockIdx.y;
    const int w    = threadIdx.x >> 6;
    const int lane = threadIdx.x & 63;
    const int r    = lane & 15;
    const int cgrp = lane >> 4;
    const int i0   = blockIdx.x * 32 + w * 16;
    const float* src = (m == 0 || m == 3) ? ni : nj;
    const short* wbase = wT + m * 65536 + cgrp * 8;

    f32x4 acc[8];
#pragma unroll
    for (int nt = 0; nt < 8; nt++) acc[nt] = (f32x4){0.0f, 0.0f, 0.0f, 0.0f};

    const float* arow = src + (size_t)(i0 + r) * C_ + cgrp * 8;
#pragma unroll 4
    for (int kk = 0; kk < 16; kk++) {
        const f32x4 a0 = *(const f32x4*)(arow + kk * 32);
        const f32x4 a1 = *(const f32x4*)(arow + kk * 32 + 4);
        bf16x8 af;
        af[0] = f2bf(a0.x); af[1] = f2bf(a0.y); af[2] = f2bf(a0.z); af[3] = f2bf(a0.w);
        af[4] = f2bf(a1.x); af[5] = f2bf(a1.y); af[6] = f2bf(a1.z); af[7] = f2bf(a1.w);
#pragma unroll
        for (int nt = 0; nt < 8; nt++) {
            const bf16x8 bf = *(const bf16x8*)(wbase + (nt * 16 + r) * 512 + kk * 32);
            acc[nt] = __builtin_amdgcn_mfma_f32_16x16x32_bf16(af, bf, acc[nt], 0, 0, 0);
        }
    }

    const int b  = i0 >> 9;
    const int il = i0 & 511;
#pragma unroll
    for (int nt = 0; nt < 8; nt++) {
        const int col = nt * 16 + r;
        if (m == 3) {
            const float bgc = bg[col];
#pragma unroll
            for (int reg = 0; reg < 4; reg++) {
                const int row = i0 + cgrp * 4 + reg;
                g_ws[(size_t)row * HD_ + col] =
                    1.0f / (1.0f + __expf(-(acc[nt][reg] + bgc)));
            }
        } else if (m == 2) {
            const int h = col >> 5, d = col & 31;
            const int j = il + cgrp * 4;
            s16x4 pk;
            pk[0] = f2bf(acc[nt][0]); pk[1] = f2bf(acc[nt][1]);
            pk[2] = f2bf(acc[nt][2]); pk[3] = f2bf(acc[nt][3]);
            *(s16x4*)(vT_bf + ((size_t)(b * H_ + h) * D_ + d) * J_ + j) = pk;
        } else {
            short* dst = (m == 0) ? q_bf : k_bf;
            const int h = col >> 5, d = col & 31;
#pragma unroll
            for (int reg = 0; reg < 4; reg++) {
                const int i = il + cgrp * 4 + reg;
                dst[((size_t)(b * H_ + h) * 512 + i) * D_ + d] = f2bf(acc[nt][reg]);
            }
        }
    }
}

// ---------------------------------------------------------------------------
// K5: out = ni + ((o*g) @ wo + bo) * node_mask. 4-row tiles.
// grid: (B*I/4), block: 256
// ---------------------------------------------------------------------------
__global__ __launch_bounds__(256) void k_out(
    const float* __restrict__ o_ws, const float* __restrict__ g_ws,
    const float* __restrict__ ni, const float* __restrict__ wo,
    const float* __restrict__ bo, const int* __restrict__ nmask,
    float* __restrict__ out)
{
    __shared__ float s_og[4 * 128];
    const int tid  = threadIdx.x;
    const int base = blockIdx.x * 4;

#pragma unroll
    for (int rep = 0; rep < 2; rep++) {
        const int flat = rep * 256 + tid;
        s_og[flat] = o_ws[(size_t)base * HD_ + flat] * g_ws[(size_t)base * HD_ + flat];
    }
    __syncthreads();

    const int c0 = tid * 2;
    float a0[4] = {0, 0, 0, 0};
    float a1[4] = {0, 0, 0, 0};

#pragma unroll 4
    for (int hd = 0; hd < HD_; hd++) {
        const float2 wv = *(const float2*)(wo + hd * C_ + c0);
#pragma unroll
        for (int r = 0; r < 4; r++) {
            const float v = s_og[r * 128 + hd];
            a0[r] += v * wv.x;
            a1[r] += v * wv.y;
        }
    }

    const float b0v = bo[c0], b1v = bo[c0 + 1];
#pragma unroll
    for (int r = 0; r < 4; r++) {
        const int row = base + r;
        const float mk = (float)nmask[row];
        const size_t off = (size_t)row * C_ + c0;
        out[off]     = ni[off]     + (a0[r] + b0v) * mk;
        out[off + 1] = ni[off + 1] + (a1[r] + b1v) * mk;
    }
}

// ---------------------------------------------------------------------------
extern "C" void kernel_launch(void* const* d_in, const int* in_sizes, int n_in,
                              void* d_out, int out_size, void* d_ws, size_t ws_size,
                              hipStream_t stream)
{
    const float* node_i = (const float*)d_in[0];
    const float* node_j = (const float*)d_in[1];
    const float* pair   = (const float*)d_in[2];
    const int*   pmask  = (const int*)d_in[3];
    const int*   nmask  = (const int*)d_in[4];
    const float* ln_i_g = (const float*)d_in[5];
    const float* ln_i_b = (const float*)d_in[6];
    const float* ln_j_g = (const float*)d_in[7];
    const float* ln_j_b = (const float*)d_in[8];
    const float* ln_p_g = (const float*)d_in[9];
    const float* ln_p_b = (const float*)d_in[10];
    const float* w_pb   = (const float*)d_in[11];
    const float* w_pg   = (const float*)d_in[12];
    const float* wq     = (const float*)d_in[13];
    const float* wk     = (const float*)d_in[14];
    const float* wv     = (const float*)d_in[15];
    const float* wg     = (const float*)d_in[16];
    const float* bg     = (const float*)d_in[17];
    const float* wo     = (const float*)d_in[18];
    const float* bo     = (const float*)d_in[19];

    float* out = (float*)d_out;
    float* ws  = (float*)d_ws;

    float* ni    = ws;                        // 1,048,576 floats
    float* nj    = ws + 1048576;              // 1,048,576
    float* g_ws  = ws + 6291456;              // 262,144    [B*I][HD]
    float* o_ws  = ws + 6553600;              // 262,144    [B*I][HD]
    short* q_bf  = (short*)(ws + 6815744);    // 262,144 shorts [BH][I][D]
    short* k_bf  = (short*)(ws + 6946816);    // 262,144 shorts [BH][J][D]
    short* vT_bf = (short*)(ws + 7077888);    // 262,144 shorts [BH][D][J]
    short* wT    = (short*)(ws + 7208960);    // 262,144 shorts [4][128][512]
    short* gwfB  = (short*)(ws + 7340032);    // 2,048 shorts
    float* AB    = ws + 7341056;              // 16 floats

    k_prep<<<dim3(1153), 256, 0, stream>>>(node_i, node_j, ln_i_g, ln_i_b,
                                           ln_j_g, ln_j_b, ln_p_g, ln_p_b,
                                           w_pb, w_pg, wq, wk, wv, wg,
                                           ni, nj, gwfB, AB, wT);
    k_proj<<<dim3(64, 4), 128, 0, stream>>>(ni, nj, wT, bg,
                                            q_bf, k_bf, vT_bf, g_ws);
    k_mega<<<dim3(512), 512, 0, stream>>>(pair, pmask, gwfB, AB,
                                          q_bf, k_bf, vT_bf, o_ws);
    k_out<<<dim3(512), 256, 0, stream>>>(o_ws, g_ws, ni, wo, bo, nmask, out);
}

// Round 8
// 171.132 us; speedup vs baseline: 1.0303x; 1.0303x over previous
//
#include <hip/hip_runtime.h>
#include <hip/hip_bf16.h>

#define B_ 4
#define I_ 512
#define J_ 512
#define C_ 512
#define P_ 128
#define H_ 4
#define D_ 32
#define HD_ 128
#define EPS_ 1e-5f
#define INF_ 1.0e9f
#define QSCALE_ 0.17677669529663689f

#define PB_BLOCKS 2048            // pair: persistent blocks (4 waves each)
#define PB_WAVES (PB_BLOCKS * 4)  // 8192 waves
#define PB_TILES 65536            // B*I*J/16
#define PB_ITERS (PB_TILES / PB_WAVES)  // 8 tiles per wave

typedef __attribute__((ext_vector_type(8))) short bf16x8;
typedef __attribute__((ext_vector_type(4))) short s16x4;
typedef __attribute__((ext_vector_type(4))) float f32x4;

// fp32 -> bf16 raw bits; plain cast lets the compiler pack v_cvt_pk_bf16_f32
__device__ __forceinline__ short f2bf(float f) {
    return __bfloat16_as_short(__float2bfloat16(f));
}

// ---------------------------------------------------------------------------
// K1: merged prep (R7 version - verified).
// grid: 1153 blocks, 256 threads
// ---------------------------------------------------------------------------
__global__ __launch_bounds__(256) void k_prep(
    const float* __restrict__ xi, const float* __restrict__ xj,
    const float* __restrict__ g_i, const float* __restrict__ b_i,
    const float* __restrict__ g_j, const float* __restrict__ b_j,
    const float* __restrict__ lng, const float* __restrict__ lnb,
    const float* __restrict__ wpb, const float* __restrict__ wpg,
    const float* __restrict__ wq, const float* __restrict__ wk,
    const float* __restrict__ wv, const float* __restrict__ wg,
    float* __restrict__ ni, float* __restrict__ nj,
    short* __restrict__ gwfB, float* __restrict__ AB,
    short* __restrict__ wT)
{
    const int bx  = blockIdx.x;
    const int tid = threadIdx.x;

    if (bx < 1024) {
        const int which = bx >> 9;
        const float* x  = which ? xj  : xi;
        const float* gg = which ? g_j : g_i;
        const float* bb = which ? b_j : b_i;
        float* o        = which ? nj  : ni;

        const int row  = (bx & 511) * 4 + (tid >> 6);
        const int lane = tid & 63;

        const float* xr = x + (size_t)row * C_ + lane * 8;
        float4 v0 = *(const float4*)xr;
        float4 v1 = *(const float4*)(xr + 4);

        float s  = v0.x + v0.y + v0.z + v0.w + v1.x + v1.y + v1.z + v1.w;
        float sq = v0.x*v0.x + v0.y*v0.y + v0.z*v0.z + v0.w*v0.w
                 + v1.x*v1.x + v1.y*v1.y + v1.z*v1.z + v1.w*v1.w;
#pragma unroll
        for (int m = 1; m <= 32; m <<= 1) {
            s  += __shfl_xor(s, m);
            sq += __shfl_xor(sq, m);
        }
        const float mean = s * (1.0f / C_);
        const float var  = sq * (1.0f / C_) - mean * mean;
        const float rstd = rsqrtf(var + EPS_);

        float4 ga  = *(const float4*)(gg + lane * 8);
        float4 gb  = *(const float4*)(gg + lane * 8 + 4);
        float4 ba  = *(const float4*)(bb + lane * 8);
        float4 bb4 = *(const float4*)(bb + lane * 8 + 4);

        float4 r0, r1;
        r0.x = (v0.x - mean) * rstd * ga.x + ba.x;
        r0.y = (v0.y - mean) * rstd * ga.y + ba.y;
        r0.z = (v0.z - mean) * rstd * ga.z + ba.z;
        r0.w = (v0.w - mean) * rstd * ga.w + ba.w;
        r1.x = (v1.x - mean) * rstd * gb.x + bb4.x;
        r1.y = (v1.y - mean) * rstd * gb.y + bb4.y;
        r1.z = (v1.z - mean) * rstd * gb.z + bb4.z;
        r1.w = (v1.w - mean) * rstd * gb.w + bb4.w;

        float* orow = o + (size_t)row * C_ + lane * 8;
        *(float4*)orow       = r0;
        *(float4*)(orow + 4) = r1;
    } else if (bx == 1024) {
        // ---- fold path ----
        __shared__ float sAB[P_ * 16];
        const int s = tid >> 6, lane = tid & 63;
        const int c = lane >> 4, n = lane & 15;
#pragma unroll
        for (int e = 0; e < 8; e++) {
            const int p = s * 32 + c * 8 + e;
            const float w = (n < 4) ? wpb[p * 4 + n]
                          : (n < 8) ? wpg[p * 4 + (n - 4)] : 0.0f;
            gwfB[(s * 64 + lane) * 8 + e] = f2bf(lng[p] * w);
        }
        if (tid < P_) {
            const int p = tid;
            const float g = lng[p], b = lnb[p];
#pragma unroll
            for (int h = 0; h < 4; h++) {
                const float wb = wpb[p * 4 + h], wgv = wpg[p * 4 + h];
                sAB[p * 16 + h]      = g * wb;
                sAB[p * 16 + 4 + h]  = g * wgv;
                sAB[p * 16 + 8 + h]  = b * wb;
                sAB[p * 16 + 12 + h] = b * wgv;
            }
        }
        __syncthreads();
        if (tid < 16) {
            float a = 0.0f;
            for (int p = 0; p < P_; p++) a += sAB[p * 16 + tid];
            AB[tid] = a;
        }
    } else {
        // ---- weight transpose: 128 blocks, 4 cols each, 8 c per thread ----
        const int bx2 = bx - 1025;          // 0..127
        const int m   = bx2 >> 5, sub = bx2 & 31;
        const float* W = (m == 0) ? wq : (m == 1) ? wk : (m == 2) ? wv : wg;
        const float scale = (m == 0) ? QSCALE_ : 1.0f;
        const int col = sub * 4 + (tid >> 6);
        const int c0  = (tid & 63) * 8;
        bf16x8 pk;
#pragma unroll
        for (int u = 0; u < 8; u++)
            pk[u] = f2bf(W[(size_t)(c0 + u) * HD_ + col] * scale);
        *(bf16x8*)(wT + m * 65536 + col * 512 + c0) = pk;
    }
}

// ---------------------------------------------------------------------------
// pair helpers: coalesced load -> regs; swizzled LDS stage; fragment compute.
// Swizzle: within-row byte offset ^= (row&7)<<4  (bijective, capacity-bound
// on both ds_write_b128 and ds_read_b128 sides).
// ---------------------------------------------------------------------------
__device__ __forceinline__ void pb_load_coal(
    f32x4 (&ld)[8], float& pm, int tile,
    const float* __restrict__ pair, const int* __restrict__ pmask,
    int lane, int r)
{
    const float* tb = pair + (size_t)tile * 2048 + lane * 4;
#pragma unroll
    for (int s = 0; s < 8; s++)
        ld[s] = *(const f32x4*)(tb + s * 256);
    pm = (float)pmask[tile * 16 + r];
}

__device__ __forceinline__ void pb_stage(
    char* __restrict__ my, const f32x4 (&ld)[8], int lane)
{
    const int half = lane >> 5;
    const int wb   = (lane & 31) * 16;
#pragma unroll
    for (int s = 0; s < 8; s++) {
        const int row = s * 2 + half;
        *(f32x4*)(my + row * 512 + (wb ^ ((row & 7) << 4))) = ld[s];
    }
}

__device__ __forceinline__ void pb_compute(
    const char* __restrict__ my, float pm, int tile,
    const bf16x8 (&bfrag)[4], float Al, float Ag, float Bl, float Bg,
    float* __restrict__ bias, int lane, int r, int c)
{
    // fragments from LDS (swizzled)
    const char* rowb = my + r * 512;
    const int swz = (r & 7) << 4;
    f32x4 xa[4], xb[4];
#pragma unroll
    for (int ss = 0; ss < 4; ss++) {
        const int b0 = c * 32 + ss * 128;
        xa[ss] = *(const f32x4*)(rowb + ((b0)      ^ swz));
        xb[ss] = *(const f32x4*)(rowb + ((b0 + 16) ^ swz));
    }

    f32x4 acc = {0.0f, 0.0f, 0.0f, 0.0f};
    float sum = 0.0f, sq = 0.0f;
#pragma unroll
    for (int s = 0; s < 4; s++) {
        const float e0 = xa[s].x, e1 = xa[s].y, e2 = xa[s].z, e3 = xa[s].w;
        const float e4 = xb[s].x, e5 = xb[s].y, e6 = xb[s].z, e7 = xb[s].w;
        sum += e0 + e1 + e2 + e3 + e4 + e5 + e6 + e7;
        sq = fmaf(e0, e0, sq); sq = fmaf(e1, e1, sq);
        sq = fmaf(e2, e2, sq); sq = fmaf(e3, e3, sq);
        sq = fmaf(e4, e4, sq); sq = fmaf(e5, e5, sq);
        sq = fmaf(e6, e6, sq); sq = fmaf(e7, e7, sq);
        bf16x8 afrag;
        afrag[0] = f2bf(e0); afrag[1] = f2bf(e1);
        afrag[2] = f2bf(e2); afrag[3] = f2bf(e3);
        afrag[4] = f2bf(e4); afrag[5] = f2bf(e5);
        afrag[6] = f2bf(e6); afrag[7] = f2bf(e7);
        acc = __builtin_amdgcn_mfma_f32_16x16x32_bf16(afrag, bfrag[s], acc, 0, 0, 0);
    }

    sum += __shfl_xor(sum, 16); sum += __shfl_xor(sum, 32);
    sq  += __shfl_xor(sq, 16);  sq  += __shfl_xor(sq, 32);
    const float mean = sum * (1.0f / P_);
    const float rstd = rsqrtf(sq * (1.0f / P_) - mean * mean + EPS_);
    const float mr   = mean * rstd;
    const float mb   = INF_ * (pm - 1.0f);

    const int base = tile * 16;
    const int j0 = base & (J_ - 1);
    const int i  = (base >> 9) & (I_ - 1);
    const int b  = base >> 18;
    const int n4 = r & 3;
    float* obase = bias + (((size_t)(b * H_ + n4) * I_ + i) << 9) + j0;

#pragma unroll
    for (int reg = 0; reg < 4; reg++) {
        const int rr = c * 4 + reg;
        const float rstd_r = __shfl(rstd, rr);
        const float mr_r   = __shfl(mr, rr);
        const float mb_r   = __shfl(mb, rr);
        const float Sg     = __shfl(acc[reg], lane + 4);  // gate col = head+4
        if (r < 4) {
            const float left = fmaf(rstd_r, acc[reg], fmaf(-mr_r, Al, Bl));
            const float glog = fmaf(rstd_r, Sg,       fmaf(-mr_r, Ag, Bg));
            const float val  = left * (1.0f / (1.0f + __expf(-glog))) + mb_r;
            obase[rr] = val;
        }
    }
}

// ---------------------------------------------------------------------------
// K2: fused pair-bias (persistent; coalesced loads + wave-private LDS
// transpose-bounce; register prefetch of next tile) + projections.
// grid: PB_BLOCKS + 128, block: 256
// ---------------------------------------------------------------------------
__global__ __launch_bounds__(256, 4) void k_fused(
    const float* __restrict__ pair, const int* __restrict__ pmask,
    const short* __restrict__ gwfB, const float* __restrict__ AB,
    float* __restrict__ bias,
    const float* __restrict__ ni, const float* __restrict__ nj,
    const short* __restrict__ wT, const float* __restrict__ bg,
    short* __restrict__ q_bf, short* __restrict__ k_bf,
    short* __restrict__ vT_bf, float* __restrict__ g_ws)
{
    __shared__ char s_stage[4 * 8192];   // 32KB: 8KB wave-private staging
    const int lane = threadIdx.x & 63;
    const int wid  = threadIdx.x >> 6;
    const int r    = lane & 15;
    const int c    = lane >> 4;

    if (blockIdx.x < PB_BLOCKS) {
        // ================= pair path =================
        const int wave = blockIdx.x * 4 + wid;
        char* my = s_stage + wid * 8192;

        bf16x8 bfrag[4];
#pragma unroll
        for (int s = 0; s < 4; s++)
            bfrag[s] = *(const bf16x8*)(gwfB + (s * 64 + lane) * 8);
        const int n4 = r & 3;
        const float Al = AB[n4], Ag = AB[4 + n4];
        const float Bl = AB[8 + n4], Bg = AB[12 + n4];

        f32x4 ld[8];
        float pm0, pm1;

        // prologue: tile 0 -> regs -> LDS
        pb_load_coal(ld, pm0, wave, pair, pmask, lane, r);
        pb_stage(my, ld, lane);

#pragma unroll
        for (int it = 0; it < PB_ITERS; it++) {
            const int t = wave + it * PB_WAVES;
            if (it + 1 < PB_ITERS)
                pb_load_coal(ld, pm1, t + PB_WAVES, pair, pmask, lane, r);
            pb_compute(my, pm0, t, bfrag, Al, Ag, Bl, Bg, bias, lane, r, c);
            if (it + 1 < PB_ITERS) {
                pb_stage(my, ld, lane);   // overwrite after compute's reads
                pm0 = pm1;
            }
        }
    } else {
        // ================= projection path =================
        const int px = blockIdx.x - PB_BLOCKS;     // 0..127
        const int m  = px >> 5;                    // 0..3 : q,k,v,g
        const int i0 = (px & 31) * 64 + wid * 16;  // row in [0, B*I)
        const float* src = (m == 0 || m == 3) ? ni : nj;
        const short* wbase = wT + m * 65536 + c * 8;

        f32x4 acc[8];
#pragma unroll
        for (int nt = 0; nt < 8; nt++) acc[nt] = (f32x4){0.0f, 0.0f, 0.0f, 0.0f};

        const float* arow = src + (size_t)(i0 + r) * C_ + c * 8;
#pragma unroll 4
        for (int kk = 0; kk < 16; kk++) {
            const f32x4 a0 = *(const f32x4*)(arow + kk * 32);
            const f32x4 a1 = *(const f32x4*)(arow + kk * 32 + 4);
            bf16x8 af;
            af[0] = f2bf(a0.x); af[1] = f2bf(a0.y); af[2] = f2bf(a0.z); af[3] = f2bf(a0.w);
            af[4] = f2bf(a1.x); af[5] = f2bf(a1.y); af[6] = f2bf(a1.z); af[7] = f2bf(a1.w);
#pragma unroll
            for (int nt = 0; nt < 8; nt++) {
                const bf16x8 bf = *(const bf16x8*)(wbase + (nt * 16 + r) * 512 + kk * 32);
                acc[nt] = __builtin_amdgcn_mfma_f32_16x16x32_bf16(af, bf, acc[nt], 0, 0, 0);
            }
        }

        const int b  = i0 >> 9;
        const int il = i0 & 511;
#pragma unroll
        for (int nt = 0; nt < 8; nt++) {
            const int col = nt * 16 + r;
            if (m == 3) {
                const float bgc = bg[col];
#pragma unroll
                for (int reg = 0; reg < 4; reg++) {
                    const int row = i0 + c * 4 + reg;
                    g_ws[(size_t)row * HD_ + col] =
                        1.0f / (1.0f + __expf(-(acc[nt][reg] + bgc)));
                }
            } else if (m == 2) {
                const int h = col >> 5, d = col & 31;
                const int j = il + c * 4;
                s16x4 pk;
                pk[0] = f2bf(acc[nt][0]); pk[1] = f2bf(acc[nt][1]);
                pk[2] = f2bf(acc[nt][2]); pk[3] = f2bf(acc[nt][3]);
                *(s16x4*)(vT_bf + ((size_t)(b * H_ + h) * D_ + d) * J_ + j) = pk;
            } else {
                short* dst = (m == 0) ? q_bf : k_bf;
                const int h = col >> 5, d = col & 31;
#pragma unroll
                for (int reg = 0; reg < 4; reg++) {
                    const int i = il + c * 4 + reg;
                    dst[((size_t)(b * H_ + h) * 512 + i) * D_ + d] = f2bf(acc[nt][reg]);
                }
            }
        }
    }
}

// ---------------------------------------------------------------------------
// K4: attention via MFMA (verified R5/R6 version).
// grid: (I/16, B*H), block: 256
// ---------------------------------------------------------------------------
__global__ __launch_bounds__(256) void k_attn(
    const short* __restrict__ q_bf, const short* __restrict__ k_bf,
    const short* __restrict__ vT_bf, const float* __restrict__ bias,
    float* __restrict__ o_ws)
{
    __shared__ short s_p[16 * 520];       // P bf16, pitch 520
    __shared__ float s_red[2 * 4 * 16];   // [max|sum][wave][row]
    __shared__ float s_o[2 * 16 * 34];    // [j-half][row][d] padded

    const int tid  = threadIdx.x;
    const int w    = tid >> 6;
    const int lane = tid & 63;
    const int r    = lane & 15;
    const int c    = lane >> 4;
    const int bh   = blockIdx.y;
    const int i0   = blockIdx.x * 16;

    const bf16x8 qf = *(const bf16x8*)(q_bf + ((size_t)bh * I_ + i0 + r) * D_ + c * 8);
    f32x4 acc[8];
#pragma unroll
    for (int t = 0; t < 8; t++) {
        const int jt = w * 8 + t;
        const float* bp = bias + ((size_t)bh * I_ + i0 + c * 4) * J_ + jt * 16 + r;
        f32x4 ci;
        ci[0] = bp[0]; ci[1] = bp[J_]; ci[2] = bp[2 * J_]; ci[3] = bp[3 * J_];
        const bf16x8 kf = *(const bf16x8*)(k_bf + ((size_t)bh * J_ + jt * 16 + r) * D_ + c * 8);
        acc[t] = __builtin_amdgcn_mfma_f32_16x16x32_bf16(qf, kf, ci, 0, 0, 0);
    }

    float mx[4];
#pragma unroll
    for (int reg = 0; reg < 4; reg++) {
        float m0 = acc[0][reg];
#pragma unroll
        for (int t = 1; t < 8; t++) m0 = fmaxf(m0, acc[t][reg]);
        mx[reg] = m0;
    }
#pragma unroll
    for (int mm = 1; mm < 16; mm <<= 1) {
#pragma unroll
        for (int reg = 0; reg < 4; reg++)
            mx[reg] = fmaxf(mx[reg], __shfl_xor(mx[reg], mm));
    }
    if (r < 4) {
        const float v = (r == 0) ? mx[0] : (r == 1) ? mx[1] : (r == 2) ? mx[2] : mx[3];
        s_red[w * 16 + c * 4 + r] = v;
    }
    __syncthreads();

    float M[4];
#pragma unroll
    for (int reg = 0; reg < 4; reg++) {
        const int row = c * 4 + reg;
        M[reg] = fmaxf(fmaxf(s_red[row], s_red[16 + row]),
                       fmaxf(s_red[32 + row], s_red[48 + row]));
    }

    float sm[4] = {0.0f, 0.0f, 0.0f, 0.0f};
#pragma unroll
    for (int t = 0; t < 8; t++) {
        const int j = (w * 8 + t) * 16 + r;
#pragma unroll
        for (int reg = 0; reg < 4; reg++) {
            const float p = __expf(acc[t][reg] - M[reg]);
            sm[reg] += p;
            s_p[(c * 4 + reg) * 520 + j] = f2bf(p);
        }
    }
#pragma unroll
    for (int mm = 1; mm < 16; mm <<= 1) {
#pragma unroll
        for (int reg = 0; reg < 4; reg++)
            sm[reg] += __shfl_xor(sm[reg], mm);
    }
    if (r < 4) {
        const float v = (r == 0) ? sm[0] : (r == 1) ? sm[1] : (r == 2) ? sm[2] : sm[3];
        s_red[64 + w * 16 + c * 4 + r] = v;
    }
    __syncthreads();

    const int nt = w & 1, jh = w >> 1;
    f32x4 oacc = {0.0f, 0.0f, 0.0f, 0.0f};
    const short* vrow = vT_bf + ((size_t)bh * D_ + nt * 16 + r) * J_ + c * 8;
#pragma unroll
    for (int kk8 = 0; kk8 < 8; kk8++) {
        const int kk = jh * 8 + kk8;
        const bf16x8 pf = *(const bf16x8*)(s_p + r * 520 + kk * 32 + c * 8);
        const bf16x8 vf = *(const bf16x8*)(vrow + kk * 32);
        oacc = __builtin_amdgcn_mfma_f32_16x16x32_bf16(pf, vf, oacc, 0, 0, 0);
    }
#pragma unroll
    for (int reg = 0; reg < 4; reg++)
        s_o[jh * 544 + (c * 4 + reg) * 34 + nt * 16 + r] = oacc[reg];
    __syncthreads();

    const int il = tid >> 4, dd = (tid & 15) * 2;
    const float den = s_red[64 + il] + s_red[64 + 16 + il]
                    + s_red[64 + 32 + il] + s_red[64 + 48 + il];
    const float rs = 1.0f / den;
    const float v0 = (s_o[il * 34 + dd]     + s_o[544 + il * 34 + dd])     * rs;
    const float v1 = (s_o[il * 34 + dd + 1] + s_o[544 + il * 34 + dd + 1]) * rs;
    const int b = bh >> 2, h = bh & 3;
    float* op = o_ws + ((size_t)(b * I_ + i0 + il)) * HD_ + h * D_ + dd;
    op[0] = v0; op[1] = v1;
}

// ---------------------------------------------------------------------------
// K5: out = ni + ((o*g) @ wo + bo) * node_mask. 4-row tiles.
// grid: (B*I/4), block: 256
// ---------------------------------------------------------------------------
__global__ __launch_bounds__(256) void k_out(
    const float* __restrict__ o_ws, const float* __restrict__ g_ws,
    const float* __restrict__ ni, const float* __restrict__ wo,
    const float* __restrict__ bo, const int* __restrict__ nmask,
    float* __restrict__ out)
{
    __shared__ float s_og[4 * 128];
    const int tid  = threadIdx.x;
    const int base = blockIdx.x * 4;

#pragma unroll
    for (int rep = 0; rep < 2; rep++) {
        const int flat = rep * 256 + tid;
        s_og[flat] = o_ws[(size_t)base * HD_ + flat] * g_ws[(size_t)base * HD_ + flat];
    }
    __syncthreads();

    const int c0 = tid * 2;
    float a0[4] = {0, 0, 0, 0};
    float a1[4] = {0, 0, 0, 0};

#pragma unroll 4
    for (int hd = 0; hd < HD_; hd++) {
        const float2 wv = *(const float2*)(wo + hd * C_ + c0);
#pragma unroll
        for (int r = 0; r < 4; r++) {
            const float v = s_og[r * 128 + hd];
            a0[r] += v * wv.x;
            a1[r] += v * wv.y;
        }
    }

    const float b0v = bo[c0], b1v = bo[c0 + 1];
#pragma unroll
    for (int r = 0; r < 4; r++) {
        const int row = base + r;
        const float mk = (float)nmask[row];
        const size_t off = (size_t)row * C_ + c0;
        out[off]     = ni[off]     + (a0[r] + b0v) * mk;
        out[off + 1] = ni[off + 1] + (a1[r] + b1v) * mk;
    }
}

// ---------------------------------------------------------------------------
extern "C" void kernel_launch(void* const* d_in, const int* in_sizes, int n_in,
                              void* d_out, int out_size, void* d_ws, size_t ws_size,
                              hipStream_t stream)
{
    const float* node_i = (const float*)d_in[0];
    const float* node_j = (const float*)d_in[1];
    const float* pair   = (const float*)d_in[2];
    const int*   pmask  = (const int*)d_in[3];
    const int*   nmask  = (const int*)d_in[4];
    const float* ln_i_g = (const float*)d_in[5];
    const float* ln_i_b = (const float*)d_in[6];
    const float* ln_j_g = (const float*)d_in[7];
    const float* ln_j_b = (const float*)d_in[8];
    const float* ln_p_g = (const float*)d_in[9];
    const float* ln_p_b = (const float*)d_in[10];
    const float* w_pb   = (const float*)d_in[11];
    const float* w_pg   = (const float*)d_in[12];
    const float* wq     = (const float*)d_in[13];
    const float* wk     = (const float*)d_in[14];
    const float* wv     = (const float*)d_in[15];
    const float* wg     = (const float*)d_in[16];
    const float* bg     = (const float*)d_in[17];
    const float* wo     = (const float*)d_in[18];
    const float* bo     = (const float*)d_in[19];

    float* out = (float*)d_out;
    float* ws  = (float*)d_ws;

    float* ni    = ws;                        // 1,048,576 floats
    float* nj    = ws + 1048576;              // 1,048,576
    float* bias  = ws + 2097152;              // 4,194,304  [B,H,I,J]
    float* g_ws  = ws + 6291456;              // 262,144    [B*I][HD]
    float* o_ws  = ws + 6553600;              // 262,144    [B*I][HD]
    short* q_bf  = (short*)(ws + 6815744);    // 262,144 shorts [BH][I][D]
    short* k_bf  = (short*)(ws + 6946816);    // 262,144 shorts [BH][J][D]
    short* vT_bf = (short*)(ws + 7077888);    // 262,144 shorts [BH][D][J]
    short* wT    = (short*)(ws + 7208960);    // 262,144 shorts [4][128][512]
    short* gwfB  = (short*)(ws + 7340032);    // 2,048 shorts
    float* AB    = ws + 7341056;              // 16 floats

    k_prep<<<dim3(1153), 256, 0, stream>>>(node_i, node_j, ln_i_g, ln_i_b,
                                           ln_j_g, ln_j_b, ln_p_g, ln_p_b,
                                           w_pb, w_pg, wq, wk, wv, wg,
                                           ni, nj, gwfB, AB, wT);
    k_fused<<<dim3(PB_BLOCKS + 128), 256, 0, stream>>>(
        pair, pmask, gwfB, AB, bias, ni, nj, wT, bg,
        q_bf, k_bf, vT_bf, g_ws);
    k_attn<<<dim3(32, 16), 256, 0, stream>>>(q_bf, k_bf, vT_bf, bias, o_ws);
    k_out<<<dim3(512), 256, 0, stream>>>(o_ws, g_ws, ni, wo, bo, nmask, out);
}

// Round 9
// 153.877 us; speedup vs baseline: 1.1459x; 1.1121x over previous
//
#include <hip/hip_runtime.h>
#include <hip/hip_bf16.h>

#define B_ 4
#define I_ 512
#define J_ 512
#define C_ 512
#define P_ 128
#define H_ 4
#define D_ 32
#define HD_ 128
#define EPS_ 1e-5f
#define INF_ 1.0e9f
#define QSCALE_ 0.17677669529663689f

#define PB_BLOCKS 2048            // pair: persistent blocks (4 waves each)
#define PB_WAVES (PB_BLOCKS * 4)  // 8192 waves
#define PB_TILES 65536            // B*I*J/16
#define PB_ITERS (PB_TILES / PB_WAVES)  // 8 tiles per wave

typedef __attribute__((ext_vector_type(8))) short bf16x8;
typedef __attribute__((ext_vector_type(4))) short s16x4;
typedef __attribute__((ext_vector_type(4))) float f32x4;

__device__ __forceinline__ short f2bf(float f) {
    return __bfloat16_as_short(__float2bfloat16(f));
}

// ---------------------------------------------------------------------------
// K1: merged prep.
//   blocks 0..1023:    LayerNorm of node_i / node_j
//   block 1024:        fold pair weights (MFMA B-frags) + AB[16]
//   blocks 1025..1152: transpose {wq,wk,wv,wg} -> wT (bf16, q-scale folded)
//   blocks 1153..1184: transpose wo -> woT[col][k] bf16
// grid: 1185 blocks, 256 threads
// ---------------------------------------------------------------------------
__global__ __launch_bounds__(256) void k_prep(
    const float* __restrict__ xi, const float* __restrict__ xj,
    const float* __restrict__ g_i, const float* __restrict__ b_i,
    const float* __restrict__ g_j, const float* __restrict__ b_j,
    const float* __restrict__ lng, const float* __restrict__ lnb,
    const float* __restrict__ wpb, const float* __restrict__ wpg,
    const float* __restrict__ wq, const float* __restrict__ wk,
    const float* __restrict__ wv, const float* __restrict__ wg,
    const float* __restrict__ wo,
    float* __restrict__ ni, float* __restrict__ nj,
    short* __restrict__ gwfB, float* __restrict__ AB,
    short* __restrict__ wT, short* __restrict__ woT)
{
    const int bx  = blockIdx.x;
    const int tid = threadIdx.x;

    if (bx < 1024) {
        const int which = bx >> 9;
        const float* x  = which ? xj  : xi;
        const float* gg = which ? g_j : g_i;
        const float* bb = which ? b_j : b_i;
        float* o        = which ? nj  : ni;

        const int row  = (bx & 511) * 4 + (tid >> 6);
        const int lane = tid & 63;

        const float* xr = x + (size_t)row * C_ + lane * 8;
        float4 v0 = *(const float4*)xr;
        float4 v1 = *(const float4*)(xr + 4);

        float s  = v0.x + v0.y + v0.z + v0.w + v1.x + v1.y + v1.z + v1.w;
        float sq = v0.x*v0.x + v0.y*v0.y + v0.z*v0.z + v0.w*v0.w
                 + v1.x*v1.x + v1.y*v1.y + v1.z*v1.z + v1.w*v1.w;
#pragma unroll
        for (int m = 1; m <= 32; m <<= 1) {
            s  += __shfl_xor(s, m);
            sq += __shfl_xor(sq, m);
        }
        const float mean = s * (1.0f / C_);
        const float var  = sq * (1.0f / C_) - mean * mean;
        const float rstd = rsqrtf(var + EPS_);

        float4 ga  = *(const float4*)(gg + lane * 8);
        float4 gb  = *(const float4*)(gg + lane * 8 + 4);
        float4 ba  = *(const float4*)(bb + lane * 8);
        float4 bb4 = *(const float4*)(bb + lane * 8 + 4);

        float4 r0, r1;
        r0.x = (v0.x - mean) * rstd * ga.x + ba.x;
        r0.y = (v0.y - mean) * rstd * ga.y + ba.y;
        r0.z = (v0.z - mean) * rstd * ga.z + ba.z;
        r0.w = (v0.w - mean) * rstd * ga.w + ba.w;
        r1.x = (v1.x - mean) * rstd * gb.x + bb4.x;
        r1.y = (v1.y - mean) * rstd * gb.y + bb4.y;
        r1.z = (v1.z - mean) * rstd * gb.z + bb4.z;
        r1.w = (v1.w - mean) * rstd * gb.w + bb4.w;

        float* orow = o + (size_t)row * C_ + lane * 8;
        *(float4*)orow       = r0;
        *(float4*)(orow + 4) = r1;
    } else if (bx == 1024) {
        __shared__ float sAB[P_ * 16];
        const int s = tid >> 6, lane = tid & 63;
        const int c = lane >> 4, n = lane & 15;
#pragma unroll
        for (int e = 0; e < 8; e++) {
            const int p = s * 32 + c * 8 + e;
            const float w = (n < 4) ? wpb[p * 4 + n]
                          : (n < 8) ? wpg[p * 4 + (n - 4)] : 0.0f;
            gwfB[(s * 64 + lane) * 8 + e] = f2bf(lng[p] * w);
        }
        if (tid < P_) {
            const int p = tid;
            const float g = lng[p], b = lnb[p];
#pragma unroll
            for (int h = 0; h < 4; h++) {
                const float wb = wpb[p * 4 + h], wgv = wpg[p * 4 + h];
                sAB[p * 16 + h]      = g * wb;
                sAB[p * 16 + 4 + h]  = g * wgv;
                sAB[p * 16 + 8 + h]  = b * wb;
                sAB[p * 16 + 12 + h] = b * wgv;
            }
        }
        __syncthreads();
        if (tid < 16) {
            float a = 0.0f;
            for (int p = 0; p < P_; p++) a += sAB[p * 16 + tid];
            AB[tid] = a;
        }
    } else if (bx < 1153) {
        // ---- wT: [m][col(128)][c(512)] bf16 ----
        const int bx2 = bx - 1025;          // 0..127
        const int m   = bx2 >> 5, sub = bx2 & 31;
        const float* W = (m == 0) ? wq : (m == 1) ? wk : (m == 2) ? wv : wg;
        const float scale = (m == 0) ? QSCALE_ : 1.0f;
        const int col = sub * 4 + (tid >> 6);
        const int c0  = (tid & 63) * 8;
        bf16x8 pk;
#pragma unroll
        for (int u = 0; u < 8; u++)
            pk[u] = f2bf(W[(size_t)(c0 + u) * HD_ + col] * scale);
        *(bf16x8*)(wT + m * 65536 + col * 512 + c0) = pk;
    } else {
        // ---- woT: [col(512)][k(128)] bf16 ----
        const int bx3 = bx - 1153;          // 0..31
        const int col = bx3 * 16 + (tid & 15);
        const int k0  = (tid >> 4) * 8;
        bf16x8 pk;
#pragma unroll
        for (int u = 0; u < 8; u++)
            pk[u] = f2bf(wo[(size_t)(k0 + u) * C_ + col]);
        *(bf16x8*)(woT + col * HD_ + k0) = pk;
    }
}

// ---------------------------------------------------------------------------
// pair helpers (R8 structure; loads now NON-TEMPORAL to bias the 512MB
// stream toward the HBM path instead of L3 retention).
// ---------------------------------------------------------------------------
__device__ __forceinline__ void pb_load_coal(
    f32x4 (&ld)[8], float& pm, int tile,
    const float* __restrict__ pair, const int* __restrict__ pmask,
    int lane, int r)
{
    const float* tb = pair + (size_t)tile * 2048 + lane * 4;
#pragma unroll
    for (int s = 0; s < 8; s++)
        ld[s] = __builtin_nontemporal_load((const f32x4*)(tb + s * 256));
    pm = (float)pmask[tile * 16 + r];
}

__device__ __forceinline__ void pb_stage(
    char* __restrict__ my, const f32x4 (&ld)[8], int lane)
{
    const int half = lane >> 5;
    const int wb   = (lane & 31) * 16;
#pragma unroll
    for (int s = 0; s < 8; s++) {
        const int row = s * 2 + half;
        *(f32x4*)(my + row * 512 + (wb ^ ((row & 7) << 4))) = ld[s];
    }
}

__device__ __forceinline__ void pb_compute(
    const char* __restrict__ my, float pm, int tile,
    const bf16x8 (&bfrag)[4], float Al, float Ag, float Bl, float Bg,
    float* __restrict__ bias, int lane, int r, int c)
{
    const char* rowb = my + r * 512;
    const int swz = (r & 7) << 4;
    f32x4 xa[4], xb[4];
#pragma unroll
    for (int ss = 0; ss < 4; ss++) {
        const int b0 = c * 32 + ss * 128;
        xa[ss] = *(const f32x4*)(rowb + ((b0)      ^ swz));
        xb[ss] = *(const f32x4*)(rowb + ((b0 + 16) ^ swz));
    }

    f32x4 acc = {0.0f, 0.0f, 0.0f, 0.0f};
    float sum = 0.0f, sq = 0.0f;
#pragma unroll
    for (int s = 0; s < 4; s++) {
        const float e0 = xa[s].x, e1 = xa[s].y, e2 = xa[s].z, e3 = xa[s].w;
        const float e4 = xb[s].x, e5 = xb[s].y, e6 = xb[s].z, e7 = xb[s].w;
        sum += e0 + e1 + e2 + e3 + e4 + e5 + e6 + e7;
        sq = fmaf(e0, e0, sq); sq = fmaf(e1, e1, sq);
        sq = fmaf(e2, e2, sq); sq = fmaf(e3, e3, sq);
        sq = fmaf(e4, e4, sq); sq = fmaf(e5, e5, sq);
        sq = fmaf(e6, e6, sq); sq = fmaf(e7, e7, sq);
        bf16x8 afrag;
        afrag[0] = f2bf(e0); afrag[1] = f2bf(e1);
        afrag[2] = f2bf(e2); afrag[3] = f2bf(e3);
        afrag[4] = f2bf(e4); afrag[5] = f2bf(e5);
        afrag[6] = f2bf(e6); afrag[7] = f2bf(e7);
        acc = __builtin_amdgcn_mfma_f32_16x16x32_bf16(afrag, bfrag[s], acc, 0, 0, 0);
    }

    sum += __shfl_xor(sum, 16); sum += __shfl_xor(sum, 32);
    sq  += __shfl_xor(sq, 16);  sq  += __shfl_xor(sq, 32);
    const float mean = sum * (1.0f / P_);
    const float rstd = rsqrtf(sq * (1.0f / P_) - mean * mean + EPS_);
    const float mr   = mean * rstd;
    const float mb   = INF_ * (pm - 1.0f);

    const int base = tile * 16;
    const int j0 = base & (J_ - 1);
    const int i  = (base >> 9) & (I_ - 1);
    const int b  = base >> 18;
    const int n4 = r & 3;
    float* obase = bias + (((size_t)(b * H_ + n4) * I_ + i) << 9) + j0;

#pragma unroll
    for (int reg = 0; reg < 4; reg++) {
        const int rr = c * 4 + reg;
        const float rstd_r = __shfl(rstd, rr);
        const float mr_r   = __shfl(mr, rr);
        const float mb_r   = __shfl(mb, rr);
        const float Sg     = __shfl(acc[reg], lane + 4);
        if (r < 4) {
            const float left = fmaf(rstd_r, acc[reg], fmaf(-mr_r, Al, Bl));
            const float glog = fmaf(rstd_r, Sg,       fmaf(-mr_r, Ag, Bg));
            const float val  = left * (1.0f / (1.0f + __expf(-glog))) + mb_r;
            obase[rr] = val;
        }
    }
}

// ---------------------------------------------------------------------------
// K2: fused pair-bias (persistent, NT loads, LDS bounce) + projections.
// grid: PB_BLOCKS + 128, block: 256
// ---------------------------------------------------------------------------
__global__ __launch_bounds__(256, 4) void k_fused(
    const float* __restrict__ pair, const int* __restrict__ pmask,
    const short* __restrict__ gwfB, const float* __restrict__ AB,
    float* __restrict__ bias,
    const float* __restrict__ ni, const float* __restrict__ nj,
    const short* __restrict__ wT, const float* __restrict__ bg,
    short* __restrict__ q_bf, short* __restrict__ k_bf,
    short* __restrict__ vT_bf, float* __restrict__ g_ws)
{
    __shared__ char s_stage[4 * 8192];
    const int lane = threadIdx.x & 63;
    const int wid  = threadIdx.x >> 6;
    const int r    = lane & 15;
    const int c    = lane >> 4;

    if (blockIdx.x < PB_BLOCKS) {
        const int wave = blockIdx.x * 4 + wid;
        char* my = s_stage + wid * 8192;

        bf16x8 bfrag[4];
#pragma unroll
        for (int s = 0; s < 4; s++)
            bfrag[s] = *(const bf16x8*)(gwfB + (s * 64 + lane) * 8);
        const int n4 = r & 3;
        const float Al = AB[n4], Ag = AB[4 + n4];
        const float Bl = AB[8 + n4], Bg = AB[12 + n4];

        f32x4 ld[8];
        float pm0, pm1;

        pb_load_coal(ld, pm0, wave, pair, pmask, lane, r);
        pb_stage(my, ld, lane);

#pragma unroll
        for (int it = 0; it < PB_ITERS; it++) {
            const int t = wave + it * PB_WAVES;
            if (it + 1 < PB_ITERS)
                pb_load_coal(ld, pm1, t + PB_WAVES, pair, pmask, lane, r);
            pb_compute(my, pm0, t, bfrag, Al, Ag, Bl, Bg, bias, lane, r, c);
            if (it + 1 < PB_ITERS) {
                pb_stage(my, ld, lane);
                pm0 = pm1;
            }
        }
    } else {
        const int px = blockIdx.x - PB_BLOCKS;
        const int m  = px >> 5;
        const int i0 = (px & 31) * 64 + wid * 16;
        const float* src = (m == 0 || m == 3) ? ni : nj;
        const short* wbase = wT + m * 65536 + c * 8;

        f32x4 acc[8];
#pragma unroll
        for (int nt = 0; nt < 8; nt++) acc[nt] = (f32x4){0.0f, 0.0f, 0.0f, 0.0f};

        const float* arow = src + (size_t)(i0 + r) * C_ + c * 8;
#pragma unroll 4
        for (int kk = 0; kk < 16; kk++) {
            const f32x4 a0 = *(const f32x4*)(arow + kk * 32);
            const f32x4 a1 = *(const f32x4*)(arow + kk * 32 + 4);
            bf16x8 af;
            af[0] = f2bf(a0.x); af[1] = f2bf(a0.y); af[2] = f2bf(a0.z); af[3] = f2bf(a0.w);
            af[4] = f2bf(a1.x); af[5] = f2bf(a1.y); af[6] = f2bf(a1.z); af[7] = f2bf(a1.w);
#pragma unroll
            for (int nt = 0; nt < 8; nt++) {
                const bf16x8 bf = *(const bf16x8*)(wbase + (nt * 16 + r) * 512 + kk * 32);
                acc[nt] = __builtin_amdgcn_mfma_f32_16x16x32_bf16(af, bf, acc[nt], 0, 0, 0);
            }
        }

        const int b  = i0 >> 9;
        const int il = i0 & 511;
#pragma unroll
        for (int nt = 0; nt < 8; nt++) {
            const int col = nt * 16 + r;
            if (m == 3) {
                const float bgc = bg[col];
#pragma unroll
                for (int reg = 0; reg < 4; reg++) {
                    const int row = i0 + c * 4 + reg;
                    g_ws[(size_t)row * HD_ + col] =
                        1.0f / (1.0f + __expf(-(acc[nt][reg] + bgc)));
                }
            } else if (m == 2) {
                const int h = col >> 5, d = col & 31;
                const int j = il + c * 4;
                s16x4 pk;
                pk[0] = f2bf(acc[nt][0]); pk[1] = f2bf(acc[nt][1]);
                pk[2] = f2bf(acc[nt][2]); pk[3] = f2bf(acc[nt][3]);
                *(s16x4*)(vT_bf + ((size_t)(b * H_ + h) * D_ + d) * J_ + j) = pk;
            } else {
                short* dst = (m == 0) ? q_bf : k_bf;
                const int h = col >> 5, d = col & 31;
#pragma unroll
                for (int reg = 0; reg < 4; reg++) {
                    const int i = il + c * 4 + reg;
                    dst[((size_t)(b * H_ + h) * 512 + i) * D_ + d] = f2bf(acc[nt][reg]);
                }
            }
        }
    }
}

// ---------------------------------------------------------------------------
// K3: fused attention + output projection + residual.
// Block = (8-i rows, b), 8 waves (512 thr).
//  QK:  wave = (h = w>>1, jh = w&1), 16 j-tiles; q rows duplicated r&7
//       (garbage A-rows only pollute ignored C-rows 8..15).
//  SM:  2-wave combine via s_red; P bf16 pitch-520 LDS per head (+pad rows).
//  PV:  wave = (h, dt); gate applied; og bf16 [16][136] (rows 8..15 pad).
//  OUT: og @ woT (K=128) + bo, + ni residual, * nmask.
// grid: (I/8, B), block: 512
// ---------------------------------------------------------------------------
__global__ __launch_bounds__(512) void k_attn2(
    const short* __restrict__ q_bf, const short* __restrict__ k_bf,
    const short* __restrict__ vT_bf, const float* __restrict__ bias,
    const float* __restrict__ g_ws, const short* __restrict__ woT,
    const float* __restrict__ ni, const float* __restrict__ bo,
    const int* __restrict__ nmask, float* __restrict__ out)
{
    __shared__ short s_p[40 * 520];     // 4 heads x 8 rows (pitch 520) + 8 pad
    __shared__ short s_og[16 * 136];    // rows 8..15 pad for MFMA reads
    __shared__ float s_red[128];        // [0:64) max, [64:128) sum

    const int tid  = threadIdx.x;
    const int w    = tid >> 6;
    const int lane = tid & 63;
    const int r    = lane & 15;
    const int c    = lane >> 4;
    const int b    = blockIdx.y;
    const int i0   = blockIdx.x * 8;

    const int h  = w >> 1;
    const int jh = w & 1;
    const size_t bhI = (size_t)(b * 4 + h) * 512;

    // ---- QK^T with bias C-init ----
    const bf16x8 qf = *(const bf16x8*)(q_bf + (bhI + i0 + (r & 7)) * 32 + c * 8);
    f32x4 acc[16];
#pragma unroll
    for (int t = 0; t < 16; t++) {
        const int jt = jh * 16 + t;
        const float* bp = bias + (bhI + i0) * 512 + jt * 16 + r;
        f32x4 ci;
#pragma unroll
        for (int reg = 0; reg < 4; reg++)
            ci[reg] = bp[(size_t)((c * 4 + reg) & 7) * 512];
        const bf16x8 kf = *(const bf16x8*)(k_bf + (bhI + jt * 16 + r) * 32 + c * 8);
        acc[t] = __builtin_amdgcn_mfma_f32_16x16x32_bf16(qf, kf, ci, 0, 0, 0);
    }

    // ---- row max over this wave's 256 j ----
    float mx[4];
#pragma unroll
    for (int reg = 0; reg < 4; reg++) {
        float m0 = acc[0][reg];
#pragma unroll
        for (int t = 1; t < 16; t++) m0 = fmaxf(m0, acc[t][reg]);
        mx[reg] = m0;
    }
#pragma unroll
    for (int mm = 1; mm < 16; mm <<= 1) {
#pragma unroll
        for (int reg = 0; reg < 4; reg++)
            mx[reg] = fmaxf(mx[reg], __shfl_xor(mx[reg], mm));
    }
    if (r < 4 && c < 2) s_red[w * 8 + c * 4 + r] = mx[r];
    __syncthreads();

    float M[4];
#pragma unroll
    for (int reg = 0; reg < 4; reg++) {
        const int row = (c * 4 + reg) & 7;
        M[reg] = fmaxf(s_red[(2 * h) * 8 + row], s_red[(2 * h + 1) * 8 + row]);
    }

    // ---- P = exp(logit - M), write bf16 LDS, accumulate sums ----
    float sm[4] = {0.0f, 0.0f, 0.0f, 0.0f};
#pragma unroll
    for (int t = 0; t < 16; t++) {
        const int j = jh * 256 + t * 16 + r;
#pragma unroll
        for (int reg = 0; reg < 4; reg++) {
            const float p = __expf(acc[t][reg] - M[reg]);
            sm[reg] += p;
            if (c < 2) s_p[h * 4160 + (c * 4 + reg) * 520 + j] = f2bf(p);
        }
    }
#pragma unroll
    for (int mm = 1; mm < 16; mm <<= 1) {
#pragma unroll
        for (int reg = 0; reg < 4; reg++)
            sm[reg] += __shfl_xor(sm[reg], mm);
    }
    if (r < 4 && c < 2) s_red[64 + w * 8 + c * 4 + r] = sm[r];
    __syncthreads();

    // ---- PV: wave = (h, dt = jh); gate; og bf16 ----
    {
        const int dt = jh;
        f32x4 oacc = {0.0f, 0.0f, 0.0f, 0.0f};
        const short* vrow = vT_bf + ((size_t)(b * 4 + h) * 32 + dt * 16 + r) * 512 + c * 8;
        const short* Pb = s_p + h * 4160 + r * 520 + c * 8;
#pragma unroll
        for (int kk = 0; kk < 16; kk++) {
            const bf16x8 pf = *(const bf16x8*)(Pb + kk * 32);
            const bf16x8 vf = *(const bf16x8*)(vrow + kk * 32);
            oacc = __builtin_amdgcn_mfma_f32_16x16x32_bf16(pf, vf, oacc, 0, 0, 0);
        }
        if (c < 2) {
            const int col = h * 32 + dt * 16 + r;
#pragma unroll
            for (int reg = 0; reg < 4; reg++) {
                const int i = c * 4 + reg;
                const float den = s_red[64 + (2 * h) * 8 + i]
                                + s_red[64 + (2 * h + 1) * 8 + i];
                const float g = g_ws[((size_t)(b * 512 + i0 + i)) * HD_ + col];
                s_og[i * 136 + col] = f2bf(oacc[reg] / den * g);
            }
        }
    }
    __syncthreads();

    // ---- out GEMM: og[8x128] @ woT -> 64 cols per wave; +bo, residual ----
    bf16x8 af[4];
#pragma unroll
    for (int ks = 0; ks < 4; ks++)
        af[ks] = *(const bf16x8*)(s_og + r * 136 + ks * 32 + c * 8);

#pragma unroll
    for (int ct = 0; ct < 4; ct++) {
        const int colt = w * 4 + ct;
        f32x4 oa = {0.0f, 0.0f, 0.0f, 0.0f};
#pragma unroll
        for (int ks = 0; ks < 4; ks++) {
            const bf16x8 bf = *(const bf16x8*)(woT + (colt * 16 + r) * HD_ + ks * 32 + c * 8);
            oa = __builtin_amdgcn_mfma_f32_16x16x32_bf16(af[ks], bf, oa, 0, 0, 0);
        }
        const int outc = colt * 16 + r;
        if (c < 2) {
            const float bov = bo[outc];
#pragma unroll
            for (int reg = 0; reg < 4; reg++) {
                const int row = b * 512 + i0 + c * 4 + reg;
                const float mk = (float)nmask[row];
                const size_t off = (size_t)row * C_ + outc;
                out[off] = ni[off] + (oa[reg] + bov) * mk;
            }
        }
    }
}

// ---------------------------------------------------------------------------
extern "C" void kernel_launch(void* const* d_in, const int* in_sizes, int n_in,
                              void* d_out, int out_size, void* d_ws, size_t ws_size,
                              hipStream_t stream)
{
    const float* node_i = (const float*)d_in[0];
    const float* node_j = (const float*)d_in[1];
    const float* pair   = (const float*)d_in[2];
    const int*   pmask  = (const int*)d_in[3];
    const int*   nmask  = (const int*)d_in[4];
    const float* ln_i_g = (const float*)d_in[5];
    const float* ln_i_b = (const float*)d_in[6];
    const float* ln_j_g = (const float*)d_in[7];
    const float* ln_j_b = (const float*)d_in[8];
    const float* ln_p_g = (const float*)d_in[9];
    const float* ln_p_b = (const float*)d_in[10];
    const float* w_pb   = (const float*)d_in[11];
    const float* w_pg   = (const float*)d_in[12];
    const float* wq     = (const float*)d_in[13];
    const float* wk     = (const float*)d_in[14];
    const float* wv     = (const float*)d_in[15];
    const float* wg     = (const float*)d_in[16];
    const float* bg     = (const float*)d_in[17];
    const float* wo     = (const float*)d_in[18];
    const float* bo     = (const float*)d_in[19];

    float* out = (float*)d_out;
    float* ws  = (float*)d_ws;

    float* ni    = ws;                        // 1,048,576 floats
    float* nj    = ws + 1048576;              // 1,048,576
    float* bias  = ws + 2097152;              // 4,194,304  [B,H,I,J]
    float* g_ws  = ws + 6291456;              // 262,144    [B*I][HD]
    short* q_bf  = (short*)(ws + 6815744);    // 262,144 shorts [BH][I][D]
    short* k_bf  = (short*)(ws + 6946816);    // 262,144 shorts [BH][J][D]
    short* vT_bf = (short*)(ws + 7077888);    // 262,144 shorts [BH][D][J]
    short* wT    = (short*)(ws + 7208960);    // 262,144 shorts [4][128][512]
    short* gwfB  = (short*)(ws + 7340032);    // 2,048 shorts
    float* AB    = ws + 7341056;              // 16 floats
    short* woT   = (short*)(ws + 7341072);    // 65,536 shorts [512][128]

    k_prep<<<dim3(1185), 256, 0, stream>>>(node_i, node_j, ln_i_g, ln_i_b,
                                           ln_j_g, ln_j_b, ln_p_g, ln_p_b,
                                           w_pb, w_pg, wq, wk, wv, wg, wo,
                                           ni, nj, gwfB, AB, wT, woT);
    k_fused<<<dim3(PB_BLOCKS + 128), 256, 0, stream>>>(
        pair, pmask, gwfB, AB, bias, ni, nj, wT, bg,
        q_bf, k_bf, vT_bf, g_ws);
    k_attn2<<<dim3(64, 4), 512, 0, stream>>>(q_bf, k_bf, vT_bf, bias,
                                             g_ws, woT, ni, bo, nmask, out);
}

// Round 10
// 140.473 us; speedup vs baseline: 1.2552x; 1.0954x over previous
//
#include <hip/hip_runtime.h>
#include <hip/hip_bf16.h>

#define B_ 4
#define I_ 512
#define J_ 512
#define C_ 512
#define P_ 128
#define H_ 4
#define D_ 32
#define HD_ 128
#define EPS_ 1e-5f
#define INF_ 1.0e9f
#define QSCALE_ 0.17677669529663689f

#define PB_BLOCKS 2048            // pair: persistent blocks (4 waves each)
#define PB_WAVES (PB_BLOCKS * 4)  // 8192 waves
#define PB_TILES 65536            // B*I*J/16
#define PB_ITERS (PB_TILES / PB_WAVES)  // 8 tiles per wave

typedef __attribute__((ext_vector_type(8))) short bf16x8;
typedef __attribute__((ext_vector_type(4))) short s16x4;
typedef __attribute__((ext_vector_type(4))) float f32x4;

__device__ __forceinline__ short f2bf(float f) {
    return __bfloat16_as_short(__float2bfloat16(f));
}
__device__ __forceinline__ float bf2f(short s) {
    return __uint_as_float(((unsigned)(unsigned short)s) << 16);
}

// ---------------------------------------------------------------------------
// K1: small prep (node-LN moved into k_fused's proj blocks).
//   block 0:       fold pair weights (MFMA B-frags) + AB[16]
//   blocks 1..128: transpose {wq,wk,wv,wg} -> wT bf16 (q-scale folded)
//   blocks 129..160: transpose wo -> woT[col][k] bf16
// grid: 161 blocks, 256 threads
// ---------------------------------------------------------------------------
__global__ __launch_bounds__(256) void k_prep(
    const float* __restrict__ lng, const float* __restrict__ lnb,
    const float* __restrict__ wpb, const float* __restrict__ wpg,
    const float* __restrict__ wq, const float* __restrict__ wk,
    const float* __restrict__ wv, const float* __restrict__ wg,
    const float* __restrict__ wo,
    short* __restrict__ gwfB, float* __restrict__ AB,
    short* __restrict__ wT, short* __restrict__ woT)
{
    const int bx  = blockIdx.x;
    const int tid = threadIdx.x;

    if (bx == 0) {
        __shared__ float sAB[P_ * 16];
        const int s = tid >> 6, lane = tid & 63;
        const int c = lane >> 4, n = lane & 15;
#pragma unroll
        for (int e = 0; e < 8; e++) {
            const int p = s * 32 + c * 8 + e;
            const float w = (n < 4) ? wpb[p * 4 + n]
                          : (n < 8) ? wpg[p * 4 + (n - 4)] : 0.0f;
            gwfB[(s * 64 + lane) * 8 + e] = f2bf(lng[p] * w);
        }
        if (tid < P_) {
            const int p = tid;
            const float g = lng[p], b = lnb[p];
#pragma unroll
            for (int h = 0; h < 4; h++) {
                const float wb = wpb[p * 4 + h], wgv = wpg[p * 4 + h];
                sAB[p * 16 + h]      = g * wb;
                sAB[p * 16 + 4 + h]  = g * wgv;
                sAB[p * 16 + 8 + h]  = b * wb;
                sAB[p * 16 + 12 + h] = b * wgv;
            }
        }
        __syncthreads();
        if (tid < 16) {
            float a = 0.0f;
            for (int p = 0; p < P_; p++) a += sAB[p * 16 + tid];
            AB[tid] = a;
        }
    } else if (bx < 129) {
        // ---- wT: [m][col(128)][c(512)] bf16 ----
        const int bx2 = bx - 1;             // 0..127
        const int m   = bx2 >> 5, sub = bx2 & 31;
        const float* W = (m == 0) ? wq : (m == 1) ? wk : (m == 2) ? wv : wg;
        const float scale = (m == 0) ? QSCALE_ : 1.0f;
        const int col = sub * 4 + (tid >> 6);
        const int c0  = (tid & 63) * 8;
        bf16x8 pk;
#pragma unroll
        for (int u = 0; u < 8; u++)
            pk[u] = f2bf(W[(size_t)(c0 + u) * HD_ + col] * scale);
        *(bf16x8*)(wT + m * 65536 + col * 512 + c0) = pk;
    } else {
        // ---- woT: [col(512)][k(128)] bf16 ----
        const int bx3 = bx - 129;           // 0..31
        const int col = bx3 * 16 + (tid & 15);
        const int k0  = (tid >> 4) * 8;
        bf16x8 pk;
#pragma unroll
        for (int u = 0; u < 8; u++)
            pk[u] = f2bf(wo[(size_t)(k0 + u) * C_ + col]);
        *(bf16x8*)(woT + col * HD_ + k0) = pk;
    }
}

// ---------------------------------------------------------------------------
// pair helpers (NT loads; wave-private swizzled LDS bounce)
// ---------------------------------------------------------------------------
__device__ __forceinline__ void pb_load_coal(
    f32x4 (&ld)[8], float& pm, int tile,
    const float* __restrict__ pair, const int* __restrict__ pmask,
    int lane, int r)
{
    const float* tb = pair + (size_t)tile * 2048 + lane * 4;
#pragma unroll
    for (int s = 0; s < 8; s++)
        ld[s] = __builtin_nontemporal_load((const f32x4*)(tb + s * 256));
    pm = (float)pmask[tile * 16 + r];
}

__device__ __forceinline__ void pb_stage(
    char* __restrict__ my, const f32x4 (&ld)[8], int lane)
{
    const int half = lane >> 5;
    const int wb   = (lane & 31) * 16;
#pragma unroll
    for (int s = 0; s < 8; s++) {
        const int row = s * 2 + half;
        *(f32x4*)(my + row * 512 + (wb ^ ((row & 7) << 4))) = ld[s];
    }
}

__device__ __forceinline__ void pb_compute(
    const char* __restrict__ my, float pm, int tile,
    const bf16x8 (&bfrag)[4], float Al, float Ag, float Bl, float Bg,
    short* __restrict__ bias_bf, int lane, int r, int c)
{
    const char* rowb = my + r * 512;
    const int swz = (r & 7) << 4;
    f32x4 xa[4], xb[4];
#pragma unroll
    for (int ss = 0; ss < 4; ss++) {
        const int b0 = c * 32 + ss * 128;
        xa[ss] = *(const f32x4*)(rowb + ((b0)      ^ swz));
        xb[ss] = *(const f32x4*)(rowb + ((b0 + 16) ^ swz));
    }

    f32x4 acc = {0.0f, 0.0f, 0.0f, 0.0f};
    float sum = 0.0f, sq = 0.0f;
#pragma unroll
    for (int s = 0; s < 4; s++) {
        const float e0 = xa[s].x, e1 = xa[s].y, e2 = xa[s].z, e3 = xa[s].w;
        const float e4 = xb[s].x, e5 = xb[s].y, e6 = xb[s].z, e7 = xb[s].w;
        sum += e0 + e1 + e2 + e3 + e4 + e5 + e6 + e7;
        sq = fmaf(e0, e0, sq); sq = fmaf(e1, e1, sq);
        sq = fmaf(e2, e2, sq); sq = fmaf(e3, e3, sq);
        sq = fmaf(e4, e4, sq); sq = fmaf(e5, e5, sq);
        sq = fmaf(e6, e6, sq); sq = fmaf(e7, e7, sq);
        bf16x8 afrag;
        afrag[0] = f2bf(e0); afrag[1] = f2bf(e1);
        afrag[2] = f2bf(e2); afrag[3] = f2bf(e3);
        afrag[4] = f2bf(e4); afrag[5] = f2bf(e5);
        afrag[6] = f2bf(e6); afrag[7] = f2bf(e7);
        acc = __builtin_amdgcn_mfma_f32_16x16x32_bf16(afrag, bfrag[s], acc, 0, 0, 0);
    }

    sum += __shfl_xor(sum, 16); sum += __shfl_xor(sum, 32);
    sq  += __shfl_xor(sq, 16);  sq  += __shfl_xor(sq, 32);
    const float mean = sum * (1.0f / P_);
    const float rstd = rsqrtf(sq * (1.0f / P_) - mean * mean + EPS_);
    const float mr   = mean * rstd;
    const float mb   = INF_ * (pm - 1.0f);

    const int base = tile * 16;
    const int j0 = base & (J_ - 1);
    const int i  = (base >> 9) & (I_ - 1);
    const int b  = base >> 18;
    const int n4 = r & 3;
    short* obase = bias_bf + (((size_t)(b * H_ + n4) * I_ + i) << 9) + j0;

#pragma unroll
    for (int reg = 0; reg < 4; reg++) {
        const int rr = c * 4 + reg;
        const float rstd_r = __shfl(rstd, rr);
        const float mr_r   = __shfl(mr, rr);
        const float mb_r   = __shfl(mb, rr);
        const float Sg     = __shfl(acc[reg], lane + 4);
        if (r < 4) {
            const float left = fmaf(rstd_r, acc[reg], fmaf(-mr_r, Al, Bl));
            const float glog = fmaf(rstd_r, Sg,       fmaf(-mr_r, Ag, Bg));
            const float val  = left * (1.0f / (1.0f + __expf(-glog))) + mb_r;
            obase[rr] = f2bf(val);
        }
    }
}

// ---------------------------------------------------------------------------
// K2: fused kernel.
//   blocks 0..127:   projections with INLINE LayerNorm (2-pass: stats, then
//                    normalize+MFMA). m==0 blocks also write ni (residual).
//   blocks 128..+PB: persistent pair-bias stream (NT loads, LDS bounce),
//                    writes bias as bf16.
// grid: 128 + PB_BLOCKS, block: 256
// ---------------------------------------------------------------------------
__global__ __launch_bounds__(256, 4) void k_fused(
    const float* __restrict__ pair, const int* __restrict__ pmask,
    const short* __restrict__ gwfB, const float* __restrict__ AB,
    short* __restrict__ bias_bf,
    const float* __restrict__ node_i, const float* __restrict__ node_j,
    const float* __restrict__ g_i, const float* __restrict__ b_i,
    const float* __restrict__ g_j, const float* __restrict__ b_j,
    const short* __restrict__ wT, const float* __restrict__ bg,
    short* __restrict__ q_bf, short* __restrict__ k_bf,
    short* __restrict__ vT_bf, float* __restrict__ g_ws,
    float* __restrict__ ni)
{
    __shared__ char s_stage[4 * 8192];
    const int lane = threadIdx.x & 63;
    const int wid  = threadIdx.x >> 6;
    const int r    = lane & 15;
    const int c    = lane >> 4;

    if (blockIdx.x >= 128) {
        // ================= pair path =================
        const int wave = (blockIdx.x - 128) * 4 + wid;
        char* my = s_stage + wid * 8192;

        bf16x8 bfrag[4];
#pragma unroll
        for (int s = 0; s < 4; s++)
            bfrag[s] = *(const bf16x8*)(gwfB + (s * 64 + lane) * 8);
        const int n4 = r & 3;
        const float Al = AB[n4], Ag = AB[4 + n4];
        const float Bl = AB[8 + n4], Bg = AB[12 + n4];

        f32x4 ld[8];
        float pm0, pm1;

        pb_load_coal(ld, pm0, wave, pair, pmask, lane, r);
        pb_stage(my, ld, lane);

#pragma unroll
        for (int it = 0; it < PB_ITERS; it++) {
            const int t = wave + it * PB_WAVES;
            if (it + 1 < PB_ITERS)
                pb_load_coal(ld, pm1, t + PB_WAVES, pair, pmask, lane, r);
            pb_compute(my, pm0, t, bfrag, Al, Ag, Bl, Bg, bias_bf, lane, r, c);
            if (it + 1 < PB_ITERS) {
                pb_stage(my, ld, lane);
                pm0 = pm1;
            }
        }
    } else {
        // ================= projection path (inline LN) =================
        const int px = blockIdx.x;
        const int m  = px >> 5;                    // 0..3 : q,k,v,g
        const int i0 = (px & 31) * 64 + wid * 16;  // row in [0, B*I)
        const float* src = (m == 0 || m == 3) ? node_i : node_j;
        const float* gam = (m == 0 || m == 3) ? g_i : g_j;
        const float* bet = (m == 0 || m == 3) ? b_i : b_j;
        const short* wbase = wT + m * 65536 + c * 8;

        // ---- pass 1: LN stats for row i0+r (lane covers cols c*8+kk*32+u) ----
        const float* arow = src + (size_t)(i0 + r) * C_ + c * 8;
        float sum = 0.0f, sq = 0.0f;
#pragma unroll
        for (int kk = 0; kk < 16; kk++) {
            const f32x4 a0 = *(const f32x4*)(arow + kk * 32);
            const f32x4 a1 = *(const f32x4*)(arow + kk * 32 + 4);
            sum += a0.x + a0.y + a0.z + a0.w + a1.x + a1.y + a1.z + a1.w;
            sq = fmaf(a0.x, a0.x, sq); sq = fmaf(a0.y, a0.y, sq);
            sq = fmaf(a0.z, a0.z, sq); sq = fmaf(a0.w, a0.w, sq);
            sq = fmaf(a1.x, a1.x, sq); sq = fmaf(a1.y, a1.y, sq);
            sq = fmaf(a1.z, a1.z, sq); sq = fmaf(a1.w, a1.w, sq);
        }
        sum += __shfl_xor(sum, 16); sum += __shfl_xor(sum, 32);
        sq  += __shfl_xor(sq, 16);  sq  += __shfl_xor(sq, 32);
        const float mean = sum * (1.0f / C_);
        const float rstd = rsqrtf(sq * (1.0f / C_) - mean * mean + EPS_);

        // ---- pass 2: normalize + MFMA ----
        f32x4 acc[8];
#pragma unroll
        for (int nt = 0; nt < 8; nt++) acc[nt] = (f32x4){0.0f, 0.0f, 0.0f, 0.0f};

#pragma unroll 4
        for (int kk = 0; kk < 16; kk++) {
            const f32x4 a0 = *(const f32x4*)(arow + kk * 32);
            const f32x4 a1 = *(const f32x4*)(arow + kk * 32 + 4);
            const f32x4 ga0 = *(const f32x4*)(gam + c * 8 + kk * 32);
            const f32x4 ga1 = *(const f32x4*)(gam + c * 8 + kk * 32 + 4);
            const f32x4 be0 = *(const f32x4*)(bet + c * 8 + kk * 32);
            const f32x4 be1 = *(const f32x4*)(bet + c * 8 + kk * 32 + 4);
            f32x4 n0, n1;
            n0.x = fmaf((a0.x - mean) * rstd, ga0.x, be0.x);
            n0.y = fmaf((a0.y - mean) * rstd, ga0.y, be0.y);
            n0.z = fmaf((a0.z - mean) * rstd, ga0.z, be0.z);
            n0.w = fmaf((a0.w - mean) * rstd, ga0.w, be0.w);
            n1.x = fmaf((a1.x - mean) * rstd, ga1.x, be1.x);
            n1.y = fmaf((a1.y - mean) * rstd, ga1.y, be1.y);
            n1.z = fmaf((a1.z - mean) * rstd, ga1.z, be1.z);
            n1.w = fmaf((a1.w - mean) * rstd, ga1.w, be1.w);
            if (m == 0) {
                float* np = ni + (size_t)(i0 + r) * C_ + c * 8 + kk * 32;
                *(f32x4*)np       = n0;
                *(f32x4*)(np + 4) = n1;
            }
            bf16x8 af;
            af[0] = f2bf(n0.x); af[1] = f2bf(n0.y); af[2] = f2bf(n0.z); af[3] = f2bf(n0.w);
            af[4] = f2bf(n1.x); af[5] = f2bf(n1.y); af[6] = f2bf(n1.z); af[7] = f2bf(n1.w);
#pragma unroll
            for (int nt = 0; nt < 8; nt++) {
                const bf16x8 bf = *(const bf16x8*)(wbase + (nt * 16 + r) * 512 + kk * 32);
                acc[nt] = __builtin_amdgcn_mfma_f32_16x16x32_bf16(af, bf, acc[nt], 0, 0, 0);
            }
        }

        const int b  = i0 >> 9;
        const int il = i0 & 511;
#pragma unroll
        for (int nt = 0; nt < 8; nt++) {
            const int col = nt * 16 + r;
            if (m == 3) {
                const float bgc = bg[col];
#pragma unroll
                for (int reg = 0; reg < 4; reg++) {
                    const int row = i0 + c * 4 + reg;
                    g_ws[(size_t)row * HD_ + col] =
                        1.0f / (1.0f + __expf(-(acc[nt][reg] + bgc)));
                }
            } else if (m == 2) {
                const int h = col >> 5, d = col & 31;
                const int j = il + c * 4;
                s16x4 pk;
                pk[0] = f2bf(acc[nt][0]); pk[1] = f2bf(acc[nt][1]);
                pk[2] = f2bf(acc[nt][2]); pk[3] = f2bf(acc[nt][3]);
                *(s16x4*)(vT_bf + ((size_t)(b * H_ + h) * D_ + d) * J_ + j) = pk;
            } else {
                short* dst = (m == 0) ? q_bf : k_bf;
                const int h = col >> 5, d = col & 31;
#pragma unroll
                for (int reg = 0; reg < 4; reg++) {
                    const int i = il + c * 4 + reg;
                    dst[((size_t)(b * H_ + h) * 512 + i) * D_ + d] = f2bf(acc[nt][reg]);
                }
            }
        }
    }
}

// ---------------------------------------------------------------------------
// K3: fused attention + output projection + residual (verified R9; bias bf16).
// grid: (I/8, B), block: 512
// ---------------------------------------------------------------------------
__global__ __launch_bounds__(512) void k_attn2(
    const short* __restrict__ q_bf, const short* __restrict__ k_bf,
    const short* __restrict__ vT_bf, const short* __restrict__ bias_bf,
    const float* __restrict__ g_ws, const short* __restrict__ woT,
    const float* __restrict__ ni, const float* __restrict__ bo,
    const int* __restrict__ nmask, float* __restrict__ out)
{
    __shared__ short s_p[40 * 520];
    __shared__ short s_og[16 * 136];
    __shared__ float s_red[128];

    const int tid  = threadIdx.x;
    const int w    = tid >> 6;
    const int lane = tid & 63;
    const int r    = lane & 15;
    const int c    = lane >> 4;
    const int b    = blockIdx.y;
    const int i0   = blockIdx.x * 8;

    const int h  = w >> 1;
    const int jh = w & 1;
    const size_t bhI = (size_t)(b * 4 + h) * 512;

    // ---- QK^T with bias C-init ----
    const bf16x8 qf = *(const bf16x8*)(q_bf + (bhI + i0 + (r & 7)) * 32 + c * 8);
    f32x4 acc[16];
#pragma unroll
    for (int t = 0; t < 16; t++) {
        const int jt = jh * 16 + t;
        const short* bp = bias_bf + (bhI + i0) * 512 + jt * 16 + r;
        f32x4 ci;
#pragma unroll
        for (int reg = 0; reg < 4; reg++)
            ci[reg] = bf2f(bp[(size_t)((c * 4 + reg) & 7) * 512]);
        const bf16x8 kf = *(const bf16x8*)(k_bf + (bhI + jt * 16 + r) * 32 + c * 8);
        acc[t] = __builtin_amdgcn_mfma_f32_16x16x32_bf16(qf, kf, ci, 0, 0, 0);
    }

    // ---- row max ----
    float mx[4];
#pragma unroll
    for (int reg = 0; reg < 4; reg++) {
        float m0 = acc[0][reg];
#pragma unroll
        for (int t = 1; t < 16; t++) m0 = fmaxf(m0, acc[t][reg]);
        mx[reg] = m0;
    }
#pragma unroll
    for (int mm = 1; mm < 16; mm <<= 1) {
#pragma unroll
        for (int reg = 0; reg < 4; reg++)
            mx[reg] = fmaxf(mx[reg], __shfl_xor(mx[reg], mm));
    }
    if (r < 4 && c < 2) s_red[w * 8 + c * 4 + r] = mx[r];
    __syncthreads();

    float M[4];
#pragma unroll
    for (int reg = 0; reg < 4; reg++) {
        const int row = (c * 4 + reg) & 7;
        M[reg] = fmaxf(s_red[(2 * h) * 8 + row], s_red[(2 * h + 1) * 8 + row]);
    }

    // ---- P = exp(logit - M) ----
    float sm[4] = {0.0f, 0.0f, 0.0f, 0.0f};
#pragma unroll
    for (int t = 0; t < 16; t++) {
        const int j = jh * 256 + t * 16 + r;
#pragma unroll
        for (int reg = 0; reg < 4; reg++) {
            const float p = __expf(acc[t][reg] - M[reg]);
            sm[reg] += p;
            if (c < 2) s_p[h * 4160 + (c * 4 + reg) * 520 + j] = f2bf(p);
        }
    }
#pragma unroll
    for (int mm = 1; mm < 16; mm <<= 1) {
#pragma unroll
        for (int reg = 0; reg < 4; reg++)
            sm[reg] += __shfl_xor(sm[reg], mm);
    }
    if (r < 4 && c < 2) s_red[64 + w * 8 + c * 4 + r] = sm[r];
    __syncthreads();

    // ---- PV + gate ----
    {
        const int dt = jh;
        f32x4 oacc = {0.0f, 0.0f, 0.0f, 0.0f};
        const short* vrow = vT_bf + ((size_t)(b * 4 + h) * 32 + dt * 16 + r) * 512 + c * 8;
        const short* Pb = s_p + h * 4160 + r * 520 + c * 8;
#pragma unroll
        for (int kk = 0; kk < 16; kk++) {
            const bf16x8 pf = *(const bf16x8*)(Pb + kk * 32);
            const bf16x8 vf = *(const bf16x8*)(vrow + kk * 32);
            oacc = __builtin_amdgcn_mfma_f32_16x16x32_bf16(pf, vf, oacc, 0, 0, 0);
        }
        if (c < 2) {
            const int col = h * 32 + dt * 16 + r;
#pragma unroll
            for (int reg = 0; reg < 4; reg++) {
                const int i = c * 4 + reg;
                const float den = s_red[64 + (2 * h) * 8 + i]
                                + s_red[64 + (2 * h + 1) * 8 + i];
                const float g = g_ws[((size_t)(b * 512 + i0 + i)) * HD_ + col];
                s_og[i * 136 + col] = f2bf(oacc[reg] / den * g);
            }
        }
    }
    __syncthreads();

    // ---- out GEMM + residual ----
    bf16x8 af[4];
#pragma unroll
    for (int ks = 0; ks < 4; ks++)
        af[ks] = *(const bf16x8*)(s_og + r * 136 + ks * 32 + c * 8);

#pragma unroll
    for (int ct = 0; ct < 4; ct++) {
        const int colt = w * 4 + ct;
        f32x4 oa = {0.0f, 0.0f, 0.0f, 0.0f};
#pragma unroll
        for (int ks = 0; ks < 4; ks++) {
            const bf16x8 bf = *(const bf16x8*)(woT + (colt * 16 + r) * HD_ + ks * 32 + c * 8);
            oa = __builtin_amdgcn_mfma_f32_16x16x32_bf16(af[ks], bf, oa, 0, 0, 0);
        }
        const int outc = colt * 16 + r;
        if (c < 2) {
            const float bov = bo[outc];
#pragma unroll
            for (int reg = 0; reg < 4; reg++) {
                const int row = b * 512 + i0 + c * 4 + reg;
                const float mk = (float)nmask[row];
                const size_t off = (size_t)row * C_ + outc;
                out[off] = ni[off] + (oa[reg] + bov) * mk;
            }
        }
    }
}

// ---------------------------------------------------------------------------
extern "C" void kernel_launch(void* const* d_in, const int* in_sizes, int n_in,
                              void* d_out, int out_size, void* d_ws, size_t ws_size,
                              hipStream_t stream)
{
    const float* node_i = (const float*)d_in[0];
    const float* node_j = (const float*)d_in[1];
    const float* pair   = (const float*)d_in[2];
    const int*   pmask  = (const int*)d_in[3];
    const int*   nmask  = (const int*)d_in[4];
    const float* ln_i_g = (const float*)d_in[5];
    const float* ln_i_b = (const float*)d_in[6];
    const float* ln_j_g = (const float*)d_in[7];
    const float* ln_j_b = (const float*)d_in[8];
    const float* ln_p_g = (const float*)d_in[9];
    const float* ln_p_b = (const float*)d_in[10];
    const float* w_pb   = (const float*)d_in[11];
    const float* w_pg   = (const float*)d_in[12];
    const float* wq     = (const float*)d_in[13];
    const float* wk     = (const float*)d_in[14];
    const float* wv     = (const float*)d_in[15];
    const float* wg     = (const float*)d_in[16];
    const float* bg     = (const float*)d_in[17];
    const float* wo     = (const float*)d_in[18];
    const float* bo     = (const float*)d_in[19];

    float* out = (float*)d_out;
    float* ws  = (float*)d_ws;

    float* ni      = ws;                       // 1,048,576 floats
    short* bias_bf = (short*)(ws + 1048576);   // 4,194,304 shorts (8 MB)
    float* g_ws    = ws + 3145728;             // 262,144 floats
    short* q_bf    = (short*)(ws + 3407872);   // 262,144 shorts
    short* k_bf    = (short*)(ws + 3538944);   // 262,144 shorts
    short* vT_bf   = (short*)(ws + 3670016);   // 262,144 shorts
    short* wT      = (short*)(ws + 3801088);   // 262,144 shorts
    short* gwfB    = (short*)(ws + 3932160);   // 2,048 shorts
    float* AB      = ws + 3933184;             // 16 floats
    short* woT     = (short*)(ws + 3933200);   // 65,536 shorts

    k_prep<<<dim3(161), 256, 0, stream>>>(ln_p_g, ln_p_b, w_pb, w_pg,
                                          wq, wk, wv, wg, wo,
                                          gwfB, AB, wT, woT);
    k_fused<<<dim3(128 + PB_BLOCKS), 256, 0, stream>>>(
        pair, pmask, gwfB, AB, bias_bf,
        node_i, node_j, ln_i_g, ln_i_b, ln_j_g, ln_j_b,
        wT, bg, q_bf, k_bf, vT_bf, g_ws, ni);
    k_attn2<<<dim3(64, 4), 512, 0, stream>>>(q_bf, k_bf, vT_bf, bias_bf,
                                             g_ws, woT, ni, bo, nmask, out);
}